// Round 2
// baseline (550.785 us; speedup 1.0000x reference)
//
#include <hip/hip_runtime.h>
#include <hip/hip_bf16.h>

#define B_ 2
#define S_ 2048
#define D_ 1024
#define H_ 16
#define DK_ 64
#define FF_ 4096
#define M_ (B_ * S_)  // 4096 rows

typedef unsigned short u16;
typedef __bf16 bf16x8 __attribute__((ext_vector_type(8)));
typedef float f32x4 __attribute__((ext_vector_type(4)));
typedef u16 u16x4 __attribute__((ext_vector_type(4)));
typedef u16 u16x8 __attribute__((ext_vector_type(8)));

__device__ __forceinline__ u16 f2bf(float f) {
  __bf16 b = (__bf16)f;
  return __builtin_bit_cast(u16, b);
}
__device__ __forceinline__ float bf2f(u16 u) {
  __bf16 b = __builtin_bit_cast(__bf16, u);
  return (float)b;
}

// async global->LDS, 16B per lane. LDS dest is wave-uniform base + lane*16.
__device__ __forceinline__ void async_lds16(const void* g, void* l) {
  __builtin_amdgcn_global_load_lds(
      (const __attribute__((address_space(1))) unsigned int*)g,
      (__attribute__((address_space(3))) unsigned int*)l, 16, 0, 0);
}

// ---------------------------------------------------------------------------
// f32 -> bf16 convert (weights)
__global__ __launch_bounds__(256) void f2b_k(const float* __restrict__ in,
                                             u16* __restrict__ out, int n4) {
  int idx = blockIdx.x * 256 + threadIdx.x;
  if (idx < n4) {
    float4 v = *(const float4*)(in + (size_t)idx * 4);
    u16x4 o;
    o[0] = f2bf(v.x); o[1] = f2bf(v.y); o[2] = f2bf(v.z); o[3] = f2bf(v.w);
    *(u16x4*)(out + (size_t)idx * 4) = o;
  }
}

// ---------------------------------------------------------------------------
// RMSNorm: f32 [rows][1024] -> bf16, block per row, 256 threads * 4 cols
__global__ __launch_bounds__(256) void rmsnorm_k(const float* __restrict__ X,
                                                 const float* __restrict__ G,
                                                 u16* __restrict__ Out) {
  const int row = blockIdx.x, tid = threadIdx.x;
  const float4 xv = *(const float4*)(X + (size_t)row * D_ + tid * 4);
  float ss = xv.x * xv.x + xv.y * xv.y + xv.z * xv.z + xv.w * xv.w;
#pragma unroll
  for (int off = 1; off < 64; off <<= 1) ss += __shfl_xor(ss, off);
  __shared__ float red[4];
  if ((tid & 63) == 0) red[tid >> 6] = ss;
  __syncthreads();
  const float tot = red[0] + red[1] + red[2] + red[3];
  const float sc = rsqrtf(tot * (1.0f / D_) + 1e-5f);
  const float4 gv = *(const float4*)(G + tid * 4);
  u16x4 o;
  o[0] = f2bf(xv.x * sc * gv.x);
  o[1] = f2bf(xv.y * sc * gv.y);
  o[2] = f2bf(xv.z * sc * gv.z);
  o[3] = f2bf(xv.w * sc * gv.w);
  *(u16x4*)(Out + (size_t)row * D_ + tid * 4) = o;
}

// ---------------------------------------------------------------------------
// RoPE in-place on bf16 [4096][1024] viewed as uints (pairs). 8192 blocks.
__global__ __launch_bounds__(256) void rope_k(unsigned int* __restrict__ buf,
                                              const int* __restrict__ pos) {
  const int idx = blockIdx.x * 256 + threadIdx.x;  // < 4096*512
  const int row = idx >> 9, p = idx & 511;
  const int i = p & 31;  // pair index within head
  unsigned int v = buf[(size_t)row * 512 + p];
  const float xr = bf2f((u16)(v & 0xffffu));
  const float xi = bf2f((u16)(v >> 16));
  const float ang =
      (float)pos[row] * __expf(-(float)i * (9.210340371976184f / 32.0f));
  float sn, cs;
  sincosf(ang, &sn, &cs);
  const float orr = xr * cs - xi * sn;
  const float oii = xr * sn + xi * cs;
  buf[(size_t)row * 512 + p] =
      (unsigned int)f2bf(orr) | ((unsigned int)f2bf(oii) << 16);
}

// ---------------------------------------------------------------------------
// V [4096][1024] bf16 -> Vt [32 bh][64 dk][2048 s] bf16 (per-head transpose)
__global__ __launch_bounds__(256) void transpose_v(const u16* __restrict__ V,
                                                   u16* __restrict__ Vt) {
  __shared__ __align__(16) u16 tile[32][64];
  const int tid = threadIdx.x;
  const int s0 = blockIdx.x * 32, bh = blockIdx.y, b = bh >> 4, h = bh & 15;
  {
    const int sr = tid >> 3, c = tid & 7;
    *(u16x8*)&tile[sr][c * 8] =
        *(const u16x8*)(V + (size_t)(b * S_ + s0 + sr) * D_ + h * DK_ + c * 8);
  }
  __syncthreads();
  {
    const int dk = tid >> 2, cs = tid & 3;
    u16x8 vv;
#pragma unroll
    for (int j = 0; j < 8; ++j) vv[j] = tile[cs * 8 + j][dk];
    *(u16x8*)(Vt + (size_t)(bh * DK_ + dk) * S_ + s0 + cs * 8) = vv;
  }
}

// ---------------------------------------------------------------------------
// GEMM: C[M,N] = A[M,K] @ Bw[N,K]^T   (bf16 in, f32 acc)
// 128x128 tile, BK=32, 256 threads (4 waves, 2x2 of 64x64).
// EPI 0: store bf16. EPI 1: f32 store of aux(f32) + acc. EPI 2: swiglu:
//        store bf16( silu(aux_bf16) * acc ). EPI 3: QKV split store, Cout is
//        Q base; Q/K/V regions are contiguous 8MB apart.
template <int EPI>
__global__ __launch_bounds__(256) void gemm_bt(const u16* __restrict__ A,
                                               const u16* __restrict__ Bw,
                                               void* __restrict__ Cout,
                                               const void* __restrict__ auxp,
                                               int N, int K) {
  __shared__ __align__(16) u16 As[128 * 32];
  __shared__ __align__(16) u16 Bs[128 * 32];
  const int tid = threadIdx.x;
  const int l = tid & 63, w = tid >> 6;
  const int m0 = blockIdx.y * 128, n0 = blockIdx.x * 128;
  const int wm = (w >> 1) * 64, wn = (w & 1) * 64;
  const int lr = l & 15, lg = l >> 4;

  f32x4 acc[4][4] = {};
  const int sA0 = w * 128;  // wave's first 16B slot (of 512)

  for (int k0 = 0; k0 < K; k0 += 32) {
#pragma unroll
    for (int inst = 0; inst < 2; ++inst) {
      const int s = sA0 + inst * 64 + l;      // slot: row = s>>2, c16 = s&3
      const int row = s >> 2, c = s & 3;
      async_lds16(A + (size_t)(m0 + row) * K + k0 + c * 8,
                  (char*)As + (sA0 + inst * 64) * 16);
      async_lds16(Bw + (size_t)(n0 + row) * K + k0 + c * 8,
                  (char*)Bs + (sA0 + inst * 64) * 16);
    }
    __syncthreads();  // drains vmcnt -> staged tile visible
    bf16x8 af[4], bfr[4];
#pragma unroll
    for (int i = 0; i < 4; ++i)
      af[i] = *(const bf16x8*)&As[(wm + i * 16 + lr) * 32 + lg * 8];
#pragma unroll
    for (int j = 0; j < 4; ++j)
      bfr[j] = *(const bf16x8*)&Bs[(wn + j * 16 + lr) * 32 + lg * 8];
#pragma unroll
    for (int i = 0; i < 4; ++i)
#pragma unroll
      for (int j = 0; j < 4; ++j)
        acc[i][j] = __builtin_amdgcn_mfma_f32_16x16x32_bf16(af[i], bfr[j],
                                                            acc[i][j], 0, 0, 0);
    __syncthreads();  // protect LDS before next stage
  }

  // epilogue: C/D layout col = l&15, row = (l>>4)*4 + t  [m89-verified]
#pragma unroll
  for (int i = 0; i < 4; ++i) {
#pragma unroll
    for (int j = 0; j < 4; ++j) {
#pragma unroll
      for (int t = 0; t < 4; ++t) {
        const int grow = m0 + wm + i * 16 + lg * 4 + t;
        const int gcol = n0 + wn + j * 16 + lr;
        const float v = acc[i][j][t];
        if (EPI == 0) {
          ((u16*)Cout)[(size_t)grow * N + gcol] = f2bf(v);
        } else if (EPI == 1) {
          const size_t idx = (size_t)grow * N + gcol;
          ((float*)Cout)[idx] = ((const float*)auxp)[idx] + v;
        } else if (EPI == 2) {
          const size_t idx = (size_t)grow * N + gcol;
          const float av = bf2f(((const u16*)auxp)[idx]);
          const float sw = av / (1.f + __expf(-av));
          ((u16*)Cout)[idx] = f2bf(sw * v);
        } else {
          // QKV split: region 0/1/2 (Q/K/V), each [4096][1024], contiguous
          u16* base = (u16*)Cout + (size_t)(gcol >> 10) * ((size_t)M_ * D_);
          base[(size_t)grow * D_ + (gcol & 1023)] = f2bf(v);
        }
      }
    }
  }
}

// ---------------------------------------------------------------------------
// Causal flash attention, barrier-free. Q,K: [4096][1024] bf16 (post-RoPE),
// Vt: [32 bh][64 dk][2048 s] bf16. O: [4096][1024] bf16.
// Grid (S/64, B*H); 4 waves, 16 q-rows each; kv tiles of 32.
// K and Vt fragments are read DIRECTLY from global (L2-resident, 256KB/head):
// no staging, no __syncthreads in the loop. Only LDS use is the per-wave
// P-transpose buffer (same-wave RAW -> hardware waitcnt, no barrier).
__global__ __launch_bounds__(256) void attn_fwd(const u16* __restrict__ Q,
                                                const u16* __restrict__ K,
                                                const u16* __restrict__ Vt,
                                                u16* __restrict__ O) {
  __shared__ __align__(16) u16 Ps[4][16 * 40];  // stride 40 (80B): no 4-way
  const int tid = threadIdx.x, l = tid & 63, w = tid >> 6;
  const int qx = (int)gridDim.x - 1 - (int)blockIdx.x;  // heavy blocks first
  const int q0 = qx * 64;
  const int bh = blockIdx.y, b = bh >> 4, h = bh & 15;
  const int q0w = q0 + w * 16;
  const int lr = l & 15, lg = l >> 4;

  bf16x8 aq[2];
  {
    const u16* qp = Q + (size_t)(b * S_ + q0w + lr) * D_ + h * DK_ + lg * 8;
    aq[0] = *(const bf16x8*)qp;
    aq[1] = *(const bf16x8*)(qp + 32);
  }
  f32x4 oacc[4] = {};
  float mrow[4], lrow[4];
#pragma unroll
  for (int t = 0; t < 4; ++t) { mrow[t] = -1e30f; lrow[t] = 0.f; }

  const u16* Kb = K + (size_t)(b * S_) * D_ + h * DK_;
  const u16* Vb = Vt + (size_t)bh * DK_ * S_;

  const int ntiles = qx * 2 + 2;
  for (int it = 0; it < ntiles; ++it) {
    const int kv0 = it * 32;
    // QK^T: B-frag = K row (kv), dk contiguous; direct global (L2 hit)
    f32x4 sf[2];
#pragma unroll
    for (int n = 0; n < 2; ++n) {
      f32x4 z = {};
      const u16* kp = Kb + (size_t)(kv0 + n * 16 + lr) * D_ + lg * 8;
      z = __builtin_amdgcn_mfma_f32_16x16x32_bf16(aq[0], *(const bf16x8*)kp, z,
                                                  0, 0, 0);
      z = __builtin_amdgcn_mfma_f32_16x16x32_bf16(
          aq[1], *(const bf16x8*)(kp + 32), z, 0, 0, 0);
      sf[n] = z;
    }
    // online softmax, rows r = lg*4+t spread over 16 lanes (cols)
    float corr[4];
#pragma unroll
    for (int t = 0; t < 4; ++t) {
      const int qrow = q0w + lg * 4 + t;
      float v0 = (kv0 + lr <= qrow) ? sf[0][t] * 0.125f : -1e30f;
      float v1 = (kv0 + 16 + lr <= qrow) ? sf[1][t] * 0.125f : -1e30f;
      float mx = fmaxf(v0, v1);
#pragma unroll
      for (int off = 1; off < 16; off <<= 1) mx = fmaxf(mx, __shfl_xor(mx, off));
      const float nm = fmaxf(mrow[t], mx);
      const float e0 = __expf(v0 - nm), e1 = __expf(v1 - nm);
      float ps = e0 + e1;
#pragma unroll
      for (int off = 1; off < 16; off <<= 1) ps += __shfl_xor(ps, off);
      corr[t] = __expf(mrow[t] - nm);
      lrow[t] = lrow[t] * corr[t] + ps;
      mrow[t] = nm;
      Ps[w][(lg * 4 + t) * 40 + lr] = f2bf(e0);
      Ps[w][(lg * 4 + t) * 40 + 16 + lr] = f2bf(e1);
    }
#pragma unroll
    for (int d = 0; d < 4; ++d)
#pragma unroll
      for (int t = 0; t < 4; ++t) oacc[d][t] *= corr[t];
    // PV: A = P (16x32) via per-wave LDS transpose; B = Vt rows, direct global
    bf16x8 ap = *(const bf16x8*)&Ps[w][lr * 40 + lg * 8];
#pragma unroll
    for (int d = 0; d < 4; ++d) {
      bf16x8 bv =
          *(const bf16x8*)(Vb + (size_t)(d * 16 + lr) * S_ + kv0 + lg * 8);
      oacc[d] = __builtin_amdgcn_mfma_f32_16x16x32_bf16(ap, bv, oacc[d], 0, 0, 0);
    }
  }
#pragma unroll
  for (int d = 0; d < 4; ++d) {
#pragma unroll
    for (int t = 0; t < 4; ++t) {
      const size_t idx =
          (size_t)(b * S_ + q0w + lg * 4 + t) * D_ + h * DK_ + d * 16 + lr;
      O[idx] = f2bf(oacc[d][t] / lrow[t]);
    }
  }
}

// ---------------------------------------------------------------------------
extern "C" void kernel_launch(void* const* d_in, const int* in_sizes, int n_in,
                              void* d_out, int out_size, void* d_ws,
                              size_t ws_size, hipStream_t stream) {
  (void)in_sizes; (void)n_in; (void)out_size; (void)ws_size;
  const float* x = (const float*)d_in[0];
  const float* wq = (const float*)d_in[1];
  const float* wk = (const float*)d_in[2];
  const float* wv = (const float*)d_in[3];
  const float* wo = (const float*)d_in[4];
  const float* w1 = (const float*)d_in[5];
  const float* w2 = (const float*)d_in[6];
  const float* w3 = (const float*)d_in[7];
  const float* g1 = (const float*)d_in[8];
  const float* g2 = (const float*)d_in[9];
  const int* tp = (const int*)d_in[10];
  float* out = (float*)d_out;

  char* ws = (char*)d_ws;
  const size_t MB = 1024u * 1024u;
  // layout (128 MB total, lifetime-reused):
  u16* wqkvb = (u16*)(ws + 0 * MB);   // [3072][1024] = 6MB
  u16* wob = (u16*)(ws + 6 * MB);
  u16* w1b = (u16*)(ws + 8 * MB);
  u16* w2b = (u16*)(ws + 16 * MB);
  u16* w3b = (u16*)(ws + 24 * MB);
  u16* hb  = (u16*)(ws + 32 * MB);    // rmsnorm1 out; later attn-out
  float* yb = (float*)(ws + 40 * MB); // 16MB f32
  u16* h2b = (u16*)(ws + 56 * MB);
  u16* Qb  = (u16*)(ws + 64 * MB);    // Q/K/V contiguous (EPI3 split store)
  u16* Kb  = (u16*)(ws + 72 * MB);
  u16* Vb  = (u16*)(ws + 80 * MB);
  u16* Vtb = (u16*)(ws + 88 * MB);
  u16* ab  = (u16*)(ws + 64 * MB);    // 32MB, reuses Q/K/V/Vt after attention
  u16* ffb = (u16*)(ws + 96 * MB);    // 32MB
  u16* aob = hb;                      // attention output (reuses h)

  // weight conversion (wq/wk/wv concatenated into wqkvb rows 0/1024/2048)
  f2b_k<<<1024, 256, 0, stream>>>(wq, wqkvb, 262144);
  f2b_k<<<1024, 256, 0, stream>>>(wk, wqkvb + 1048576, 262144);
  f2b_k<<<1024, 256, 0, stream>>>(wv, wqkvb + 2097152, 262144);
  f2b_k<<<1024, 256, 0, stream>>>(wo, wob, 262144);
  f2b_k<<<4096, 256, 0, stream>>>(w1, w1b, 1048576);
  f2b_k<<<4096, 256, 0, stream>>>(w2, w2b, 1048576);
  f2b_k<<<4096, 256, 0, stream>>>(w3, w3b, 1048576);

  rmsnorm_k<<<4096, 256, 0, stream>>>(x, g1, hb);

  // fused QKV projection: N=3072, split-stored into Qb/Kb/Vb
  gemm_bt<3><<<dim3(24, 32), 256, 0, stream>>>(hb, wqkvb, Qb, nullptr, 3072,
                                               1024);

  rope_k<<<8192, 256, 0, stream>>>((unsigned int*)Qb, tp);
  rope_k<<<8192, 256, 0, stream>>>((unsigned int*)Kb, tp);
  transpose_v<<<dim3(64, 32), 256, 0, stream>>>(Vb, Vtb);

  attn_fwd<<<dim3(32, 32), 256, 0, stream>>>(Qb, Kb, Vtb, aob);

  const dim3 gN1(8, 32), gN4(32, 32);  // (N/128, M/128)
  gemm_bt<1><<<gN1, 256, 0, stream>>>(aob, wob, yb, x, 1024, 1024);  // y = x + attn@wo^T
  rmsnorm_k<<<4096, 256, 0, stream>>>(yb, g2, h2b);

  gemm_bt<0><<<gN4, 256, 0, stream>>>(h2b, w1b, ab, nullptr, 4096, 1024);  // a
  gemm_bt<2><<<gN4, 256, 0, stream>>>(h2b, w3b, ffb, ab, 4096, 1024);      // silu(a)*gate
  gemm_bt<1><<<gN1, 256, 0, stream>>>(ffb, w2b, out, yb, 1024, 4096);      // y + ff
}

// Round 3
// 410.546 us; speedup vs baseline: 1.3416x; 1.3416x over previous
//
#include <hip/hip_runtime.h>
#include <hip/hip_bf16.h>

#define B_ 2
#define S_ 2048
#define D_ 1024
#define H_ 16
#define DK_ 64
#define FF_ 4096
#define M_ (B_ * S_)  // 4096 rows

typedef unsigned short u16;
typedef __bf16 bf16x8 __attribute__((ext_vector_type(8)));
typedef float f32x4 __attribute__((ext_vector_type(4)));
typedef u16 u16x4 __attribute__((ext_vector_type(4)));
typedef u16 u16x8 __attribute__((ext_vector_type(8)));

__device__ __forceinline__ u16 f2bf(float f) {
  __bf16 b = (__bf16)f;
  return __builtin_bit_cast(u16, b);
}
__device__ __forceinline__ float bf2f(u16 u) {
  __bf16 b = __builtin_bit_cast(__bf16, u);
  return (float)b;
}

// async global->LDS, 16B per lane. LDS dest is wave-uniform base + lane*16.
__device__ __forceinline__ void async_lds16(const void* g, void* l) {
  __builtin_amdgcn_global_load_lds(
      (const __attribute__((address_space(1))) unsigned int*)g,
      (__attribute__((address_space(3))) unsigned int*)l, 16, 0, 0);
}

// ---------------------------------------------------------------------------
// f32 -> bf16 convert (weights)
__global__ __launch_bounds__(256) void f2b_k(const float* __restrict__ in,
                                             u16* __restrict__ out, int n4) {
  int idx = blockIdx.x * 256 + threadIdx.x;
  if (idx < n4) {
    float4 v = *(const float4*)(in + (size_t)idx * 4);
    u16x4 o;
    o[0] = f2bf(v.x); o[1] = f2bf(v.y); o[2] = f2bf(v.z); o[3] = f2bf(v.w);
    *(u16x4*)(out + (size_t)idx * 4) = o;
  }
}

// ---------------------------------------------------------------------------
// RMSNorm: f32 [rows][1024] -> bf16, block per row, 256 threads * 4 cols
__global__ __launch_bounds__(256) void rmsnorm_k(const float* __restrict__ X,
                                                 const float* __restrict__ G,
                                                 u16* __restrict__ Out) {
  const int row = blockIdx.x, tid = threadIdx.x;
  const float4 xv = *(const float4*)(X + (size_t)row * D_ + tid * 4);
  float ss = xv.x * xv.x + xv.y * xv.y + xv.z * xv.z + xv.w * xv.w;
#pragma unroll
  for (int off = 1; off < 64; off <<= 1) ss += __shfl_xor(ss, off);
  __shared__ float red[4];
  if ((tid & 63) == 0) red[tid >> 6] = ss;
  __syncthreads();
  const float tot = red[0] + red[1] + red[2] + red[3];
  const float sc = rsqrtf(tot * (1.0f / D_) + 1e-5f);
  const float4 gv = *(const float4*)(G + tid * 4);
  u16x4 o;
  o[0] = f2bf(xv.x * sc * gv.x);
  o[1] = f2bf(xv.y * sc * gv.y);
  o[2] = f2bf(xv.z * sc * gv.z);
  o[3] = f2bf(xv.w * sc * gv.w);
  *(u16x4*)(Out + (size_t)row * D_ + tid * 4) = o;
}

// ---------------------------------------------------------------------------
// RoPE in-place on bf16 [4096][1024] viewed as uints (pairs). 8192 blocks.
__global__ __launch_bounds__(256) void rope_k(unsigned int* __restrict__ buf,
                                              const int* __restrict__ pos) {
  const int idx = blockIdx.x * 256 + threadIdx.x;  // < 4096*512
  const int row = idx >> 9, p = idx & 511;
  const int i = p & 31;  // pair index within head
  unsigned int v = buf[(size_t)row * 512 + p];
  const float xr = bf2f((u16)(v & 0xffffu));
  const float xi = bf2f((u16)(v >> 16));
  const float ang =
      (float)pos[row] * __expf(-(float)i * (9.210340371976184f / 32.0f));
  float sn, cs;
  sincosf(ang, &sn, &cs);
  const float orr = xr * cs - xi * sn;
  const float oii = xr * sn + xi * cs;
  buf[(size_t)row * 512 + p] =
      (unsigned int)f2bf(orr) | ((unsigned int)f2bf(oii) << 16);
}

// ---------------------------------------------------------------------------
// V [4096][1024] bf16 -> Vt [32 bh][64 dk][2048 s] bf16 (per-head transpose)
__global__ __launch_bounds__(256) void transpose_v(const u16* __restrict__ V,
                                                   u16* __restrict__ Vt) {
  __shared__ __align__(16) u16 tile[32][64];
  const int tid = threadIdx.x;
  const int s0 = blockIdx.x * 32, bh = blockIdx.y, b = bh >> 4, h = bh & 15;
  {
    const int sr = tid >> 3, c = tid & 7;
    *(u16x8*)&tile[sr][c * 8] =
        *(const u16x8*)(V + (size_t)(b * S_ + s0 + sr) * D_ + h * DK_ + c * 8);
  }
  __syncthreads();
  {
    const int dk = tid >> 2, cs = tid & 3;
    u16x8 vv;
#pragma unroll
    for (int j = 0; j < 8; ++j) vv[j] = tile[cs * 8 + j][dk];
    *(u16x8*)(Vt + (size_t)(bh * DK_ + dk) * S_ + s0 + cs * 8) = vv;
  }
}

// ---------------------------------------------------------------------------
// GEMM: C[M,N] = A[M,K] @ Bw[N,K]^T   (bf16 in, f32 acc)
// 128x128 tile, BK=32, 256 threads (4 waves, 2x2 of 64x64).
// XCD-chunked block swizzle (bijective: all grids have nwg % 8 == 0).
// EPI 0: store bf16. EPI 1: f32 store of aux(f32) + acc. EPI 2: swiglu:
//        store bf16( silu(aux_bf16) * acc ). EPI 3: QKV split store.
template <int EPI>
__global__ __launch_bounds__(256) void gemm_bt(const u16* __restrict__ A,
                                               const u16* __restrict__ Bw,
                                               void* __restrict__ Cout,
                                               const void* __restrict__ auxp,
                                               int N, int K) {
  __shared__ __align__(16) u16 As[128 * 32];
  __shared__ __align__(16) u16 Bs[128 * 32];
  const int tid = threadIdx.x;
  const int l = tid & 63, w = tid >> 6;
  // XCD swizzle: id%8 = XCD -> contiguous chunk of (by,bx) space per XCD
  const int gx = gridDim.x;
  const int nwg = gx * (int)gridDim.y;
  const int id = blockIdx.y * gx + blockIdx.x;
  const int swz = (id & 7) * (nwg >> 3) + (id >> 3);
  const int m0 = (swz / gx) * 128, n0 = (swz % gx) * 128;
  const int wm = (w >> 1) * 64, wn = (w & 1) * 64;
  const int lr = l & 15, lg = l >> 4;

  f32x4 acc[4][4] = {};
  const int sA0 = w * 128;  // wave's first 16B slot (of 512)

  for (int k0 = 0; k0 < K; k0 += 32) {
#pragma unroll
    for (int inst = 0; inst < 2; ++inst) {
      const int s = sA0 + inst * 64 + l;      // slot: row = s>>2, c16 = s&3
      const int row = s >> 2, c = s & 3;
      async_lds16(A + (size_t)(m0 + row) * K + k0 + c * 8,
                  (char*)As + (sA0 + inst * 64) * 16);
      async_lds16(Bw + (size_t)(n0 + row) * K + k0 + c * 8,
                  (char*)Bs + (sA0 + inst * 64) * 16);
    }
    __syncthreads();  // drains vmcnt -> staged tile visible
    bf16x8 af[4], bfr[4];
#pragma unroll
    for (int i = 0; i < 4; ++i)
      af[i] = *(const bf16x8*)&As[(wm + i * 16 + lr) * 32 + lg * 8];
#pragma unroll
    for (int j = 0; j < 4; ++j)
      bfr[j] = *(const bf16x8*)&Bs[(wn + j * 16 + lr) * 32 + lg * 8];
#pragma unroll
    for (int i = 0; i < 4; ++i)
#pragma unroll
      for (int j = 0; j < 4; ++j)
        acc[i][j] = __builtin_amdgcn_mfma_f32_16x16x32_bf16(af[i], bfr[j],
                                                            acc[i][j], 0, 0, 0);
    __syncthreads();  // protect LDS before next stage
  }

  // epilogue: C/D layout col = l&15, row = (l>>4)*4 + t  [m89-verified]
#pragma unroll
  for (int i = 0; i < 4; ++i) {
#pragma unroll
    for (int j = 0; j < 4; ++j) {
#pragma unroll
      for (int t = 0; t < 4; ++t) {
        const int grow = m0 + wm + i * 16 + lg * 4 + t;
        const int gcol = n0 + wn + j * 16 + lr;
        const float v = acc[i][j][t];
        if (EPI == 0) {
          ((u16*)Cout)[(size_t)grow * N + gcol] = f2bf(v);
        } else if (EPI == 1) {
          const size_t idx = (size_t)grow * N + gcol;
          ((float*)Cout)[idx] = ((const float*)auxp)[idx] + v;
        } else if (EPI == 2) {
          const size_t idx = (size_t)grow * N + gcol;
          const float av = bf2f(((const u16*)auxp)[idx]);
          const float sw = av / (1.f + __expf(-av));
          ((u16*)Cout)[idx] = f2bf(sw * v);
        } else {
          // QKV split: region 0/1/2 (Q/K/V), each [4096][1024], contiguous
          u16* base = (u16*)Cout + (size_t)(gcol >> 10) * ((size_t)M_ * D_);
          base[(size_t)grow * D_ + (gcol & 1023)] = f2bf(v);
        }
      }
    }
  }
}

// ---------------------------------------------------------------------------
// Causal flash attention. Q,K: [4096][1024] bf16 (post-RoPE),
// Vt: [32 bh][64 dk][2048 s] bf16. O: [4096][1024] bf16.
// 1D grid of 1024 blocks, XCD-chunked: XCD c owns heads [4c,4c+4), heavy
// (high-qx) blocks first within each head. 4 waves x 16 q-rows, KVBLK=64,
// double-buffered LDS (one barrier per tile), XOR-swizzled K and V tiles
// (pre-swizzled global source, linear LDS dest -> conflict-free ds_read_b128).
__global__ __launch_bounds__(256) void attn_fwd(const u16* __restrict__ Q,
                                                const u16* __restrict__ K,
                                                const u16* __restrict__ Vt,
                                                u16* __restrict__ O) {
  __shared__ __align__(16) u16 Ks[2][64 * 64];  // [kv][dk] 8KB each
  __shared__ __align__(16) u16 Vs[2][64 * 64];  // [dk][kv] 8KB each
  __shared__ __align__(16) u16 Ps[4][16 * 72];  // per-wave P, stride 72
  const int tid = threadIdx.x, l = tid & 63, w = tid >> 6;
  const int lr = l & 15, lg = l >> 4;
  const int bid = blockIdx.x;
  const int xcd = bid & 7, i = bid >> 3;      // i in [0,128)
  const int bh = xcd * 4 + (i >> 5);          // 4 heads per XCD
  const int qx = 31 - (i & 31);               // heavy first
  const int b = bh >> 4, h = bh & 15;
  const int q0w = qx * 64 + w * 16;

  const u16* Kb = K + (size_t)(b * S_) * D_ + h * DK_;
  const u16* Vb = Vt + (size_t)bh * DK_ * S_;

  bf16x8 aq[2];
  {
    const u16* qp = Q + (size_t)(b * S_ + q0w + lr) * D_ + h * DK_ + lg * 8;
    aq[0] = *(const bf16x8*)qp;
    aq[1] = *(const bf16x8*)(qp + 32);
  }
  f32x4 oacc[4] = {};
  float mrow[4], lrow[4];
#pragma unroll
  for (int t = 0; t < 4; ++t) { mrow[t] = -1e30f; lrow[t] = 0.f; }

  const int ntiles = qx + 1;

  // stage kv-tile t into buffer bf: K 64x64 (row=kv) and V 64x64 (row=dk),
  // both XOR-chunk-swizzled via the global source address (LDS dest linear).
  auto STAGE = [&](int bf, int t) {
#pragma unroll
    for (int inst = 0; inst < 2; ++inst) {
      const int s = (w * 2 + inst) * 64 + l;  // slot 0..511 (16B each)
      const int r = s >> 3, ch = s & 7;       // row, 16B-chunk within row
      const int chs = ch ^ (r & 7);           // source chunk (swizzle)
      async_lds16(Kb + (size_t)(t * 64 + r) * D_ + chs * 8,
                  (char*)Ks[bf] + (w * 2 + inst) * 1024);
      async_lds16(Vb + (size_t)r * S_ + t * 64 + chs * 8,
                  (char*)Vs[bf] + (w * 2 + inst) * 1024);
    }
  };

  STAGE(0, 0);
  __syncthreads();
  int cur = 0;
  for (int it = 0; it < ntiles; ++it) {
    if (it + 1 < ntiles) STAGE(cur ^ 1, it + 1);  // overlap with compute
    const int kv0 = it * 64;
    // QK^T: S[16q][64kv] per wave
    f32x4 sf[4];
#pragma unroll
    for (int n = 0; n < 4; ++n) {
      const int kvr = n * 16 + lr;
      f32x4 z = {};
#pragma unroll
      for (int ss = 0; ss < 2; ++ss) {
        const int cw = ss * 4 + lg;
        bf16x8 bk = *(const bf16x8*)&Ks[cur][kvr * 64 + ((cw ^ (kvr & 7)) * 8)];
        z = __builtin_amdgcn_mfma_f32_16x16x32_bf16(aq[ss], bk, z, 0, 0, 0);
      }
      sf[n] = z;
    }
    // online softmax: rows r = lg*4+t, cols across 16 lanes x 4 frags
    float corr[4];
#pragma unroll
    for (int t = 0; t < 4; ++t) {
      const int qrow = q0w + lg * 4 + t;
      float v[4];
#pragma unroll
      for (int n = 0; n < 4; ++n)
        v[n] = (kv0 + n * 16 + lr <= qrow) ? sf[n][t] * 0.125f : -1e30f;
      float mx = fmaxf(fmaxf(v[0], v[1]), fmaxf(v[2], v[3]));
#pragma unroll
      for (int off = 1; off < 16; off <<= 1) mx = fmaxf(mx, __shfl_xor(mx, off));
      const float nm = fmaxf(mrow[t], mx);
      float e[4], ps = 0.f;
#pragma unroll
      for (int n = 0; n < 4; ++n) { e[n] = __expf(v[n] - nm); ps += e[n]; }
#pragma unroll
      for (int off = 1; off < 16; off <<= 1) ps += __shfl_xor(ps, off);
      corr[t] = __expf(mrow[t] - nm);
      lrow[t] = lrow[t] * corr[t] + ps;
      mrow[t] = nm;
#pragma unroll
      for (int n = 0; n < 4; ++n)
        Ps[w][(lg * 4 + t) * 72 + n * 16 + lr] = f2bf(e[n]);
    }
#pragma unroll
    for (int d = 0; d < 4; ++d)
#pragma unroll
      for (int t = 0; t < 4; ++t) oacc[d][t] *= corr[t];
    // PV: A = P (16x64, per-wave LDS, same-wave RAW), B = V tile
    bf16x8 ap0 = *(const bf16x8*)&Ps[w][lr * 72 + lg * 8];
    bf16x8 ap1 = *(const bf16x8*)&Ps[w][lr * 72 + 32 + lg * 8];
#pragma unroll
    for (int d = 0; d < 4; ++d) {
      const int row = d * 16 + lr;
      bf16x8 bv0 = *(const bf16x8*)&Vs[cur][row * 64 + ((lg ^ (row & 7)) * 8)];
      bf16x8 bv1 =
          *(const bf16x8*)&Vs[cur][row * 64 + (((4 + lg) ^ (row & 7)) * 8)];
      oacc[d] = __builtin_amdgcn_mfma_f32_16x16x32_bf16(ap0, bv0, oacc[d], 0, 0, 0);
      oacc[d] = __builtin_amdgcn_mfma_f32_16x16x32_bf16(ap1, bv1, oacc[d], 0, 0, 0);
    }
    __syncthreads();  // tile it+1 staged (vmcnt drain) + cur safe to reuse
    cur ^= 1;
  }
#pragma unroll
  for (int d = 0; d < 4; ++d) {
#pragma unroll
    for (int t = 0; t < 4; ++t) {
      const size_t idx =
          (size_t)(b * S_ + q0w + lg * 4 + t) * D_ + h * DK_ + d * 16 + lr;
      O[idx] = f2bf(oacc[d][t] / lrow[t]);
    }
  }
}

// ---------------------------------------------------------------------------
extern "C" void kernel_launch(void* const* d_in, const int* in_sizes, int n_in,
                              void* d_out, int out_size, void* d_ws,
                              size_t ws_size, hipStream_t stream) {
  (void)in_sizes; (void)n_in; (void)out_size; (void)ws_size;
  const float* x = (const float*)d_in[0];
  const float* wq = (const float*)d_in[1];
  const float* wk = (const float*)d_in[2];
  const float* wv = (const float*)d_in[3];
  const float* wo = (const float*)d_in[4];
  const float* w1 = (const float*)d_in[5];
  const float* w2 = (const float*)d_in[6];
  const float* w3 = (const float*)d_in[7];
  const float* g1 = (const float*)d_in[8];
  const float* g2 = (const float*)d_in[9];
  const int* tp = (const int*)d_in[10];
  float* out = (float*)d_out;

  char* ws = (char*)d_ws;
  const size_t MB = 1024u * 1024u;
  // layout (128 MB total, lifetime-reused):
  u16* wqkvb = (u16*)(ws + 0 * MB);   // [3072][1024] = 6MB
  u16* wob = (u16*)(ws + 6 * MB);
  u16* w1b = (u16*)(ws + 8 * MB);
  u16* w2b = (u16*)(ws + 16 * MB);
  u16* w3b = (u16*)(ws + 24 * MB);
  u16* hb  = (u16*)(ws + 32 * MB);    // rmsnorm1 out; later attn-out
  float* yb = (float*)(ws + 40 * MB); // 16MB f32
  u16* h2b = (u16*)(ws + 56 * MB);
  u16* Qb  = (u16*)(ws + 64 * MB);    // Q/K/V contiguous (EPI3 split store)
  u16* Kb  = (u16*)(ws + 72 * MB);
  u16* Vb  = (u16*)(ws + 80 * MB);
  u16* Vtb = (u16*)(ws + 88 * MB);
  u16* ab  = (u16*)(ws + 64 * MB);    // 32MB, reuses Q/K/V/Vt after attention
  u16* ffb = (u16*)(ws + 96 * MB);    // 32MB
  u16* aob = hb;                      // attention output (reuses h)

  // weight conversion (wq/wk/wv concatenated into wqkvb rows 0/1024/2048)
  f2b_k<<<1024, 256, 0, stream>>>(wq, wqkvb, 262144);
  f2b_k<<<1024, 256, 0, stream>>>(wk, wqkvb + 1048576, 262144);
  f2b_k<<<1024, 256, 0, stream>>>(wv, wqkvb + 2097152, 262144);
  f2b_k<<<1024, 256, 0, stream>>>(wo, wob, 262144);
  f2b_k<<<4096, 256, 0, stream>>>(w1, w1b, 1048576);
  f2b_k<<<4096, 256, 0, stream>>>(w2, w2b, 1048576);
  f2b_k<<<4096, 256, 0, stream>>>(w3, w3b, 1048576);

  rmsnorm_k<<<4096, 256, 0, stream>>>(x, g1, hb);

  // fused QKV projection: N=3072, split-stored into Qb/Kb/Vb
  gemm_bt<3><<<dim3(24, 32), 256, 0, stream>>>(hb, wqkvb, Qb, nullptr, 3072,
                                               1024);

  rope_k<<<8192, 256, 0, stream>>>((unsigned int*)Qb, tp);
  rope_k<<<8192, 256, 0, stream>>>((unsigned int*)Kb, tp);
  transpose_v<<<dim3(64, 32), 256, 0, stream>>>(Vb, Vtb);

  attn_fwd<<<1024, 256, 0, stream>>>(Qb, Kb, Vtb, aob);

  const dim3 gN1(8, 32), gN4(32, 32);  // (N/128, M/128)
  gemm_bt<1><<<gN1, 256, 0, stream>>>(aob, wob, yb, x, 1024, 1024);  // y = x + attn@wo^T
  rmsnorm_k<<<4096, 256, 0, stream>>>(yb, g2, h2b);

  gemm_bt<0><<<gN4, 256, 0, stream>>>(h2b, w1b, ab, nullptr, 4096, 1024);  // a
  gemm_bt<2><<<gN4, 256, 0, stream>>>(h2b, w3b, ffb, ab, 4096, 1024);      // silu(a)*gate
  gemm_bt<1><<<gN1, 256, 0, stream>>>(ffb, w2b, out, yb, 1024, 4096);      // y + ff
}

// Round 4
// 362.847 us; speedup vs baseline: 1.5180x; 1.1315x over previous
//
#include <hip/hip_runtime.h>
#include <hip/hip_bf16.h>

#define B_ 2
#define S_ 2048
#define D_ 1024
#define H_ 16
#define DK_ 64
#define FF_ 4096
#define M_ (B_ * S_)  // 4096 rows

typedef unsigned short u16;
typedef __bf16 bf16x8 __attribute__((ext_vector_type(8)));
typedef float f32x4 __attribute__((ext_vector_type(4)));
typedef u16 u16x4 __attribute__((ext_vector_type(4)));
typedef u16 u16x8 __attribute__((ext_vector_type(8)));

__device__ __forceinline__ u16 f2bf(float f) {
  __bf16 b = (__bf16)f;
  return __builtin_bit_cast(u16, b);
}
__device__ __forceinline__ float bf2f(u16 u) {
  __bf16 b = __builtin_bit_cast(__bf16, u);
  return (float)b;
}

// async global->LDS, 16B per lane. LDS dest is wave-uniform base + lane*16.
__device__ __forceinline__ void async_lds16(const void* g, void* l) {
  __builtin_amdgcn_global_load_lds(
      (const __attribute__((address_space(1))) unsigned int*)g,
      (__attribute__((address_space(3))) unsigned int*)l, 16, 0, 0);
}

// ---------------------------------------------------------------------------
// All weights f32 -> bf16 in ONE dispatch. 16M f32 elems = 4M float4.
__global__ __launch_bounds__(256) void f2b_all(
    const float* __restrict__ wq, const float* __restrict__ wk,
    const float* __restrict__ wv, const float* __restrict__ wo,
    const float* __restrict__ w1, const float* __restrict__ w2,
    const float* __restrict__ w3, u16* __restrict__ wqkvb,
    u16* __restrict__ wob, u16* __restrict__ w1b, u16* __restrict__ w2b,
    u16* __restrict__ w3b) {
  int i4 = blockIdx.x * 256 + threadIdx.x;  // < 4M
  const float* src;
  u16* dst;
  int off;
  if (i4 < 262144) { src = wq; dst = wqkvb; off = i4; }
  else if (i4 < 524288) { src = wk; dst = wqkvb + 1048576; off = i4 - 262144; }
  else if (i4 < 786432) { src = wv; dst = wqkvb + 2097152; off = i4 - 524288; }
  else if (i4 < 1048576) { src = wo; dst = wob; off = i4 - 786432; }
  else if (i4 < 2097152) { src = w1; dst = w1b; off = i4 - 1048576; }
  else if (i4 < 3145728) { src = w2; dst = w2b; off = i4 - 2097152; }
  else { src = w3; dst = w3b; off = i4 - 3145728; }
  float4 v = ((const float4*)src)[off];
  u16x4 o;
  o[0] = f2bf(v.x); o[1] = f2bf(v.y); o[2] = f2bf(v.z); o[3] = f2bf(v.w);
  *(u16x4*)(dst + (size_t)off * 4) = o;
}

// ---------------------------------------------------------------------------
// RMSNorm: f32 [rows][1024] -> bf16, block per row, 256 threads * 4 cols
__global__ __launch_bounds__(256) void rmsnorm_k(const float* __restrict__ X,
                                                 const float* __restrict__ G,
                                                 u16* __restrict__ Out) {
  const int row = blockIdx.x, tid = threadIdx.x;
  const float4 xv = *(const float4*)(X + (size_t)row * D_ + tid * 4);
  float ss = xv.x * xv.x + xv.y * xv.y + xv.z * xv.z + xv.w * xv.w;
#pragma unroll
  for (int off = 1; off < 64; off <<= 1) ss += __shfl_xor(ss, off);
  __shared__ float red[4];
  if ((tid & 63) == 0) red[tid >> 6] = ss;
  __syncthreads();
  const float tot = red[0] + red[1] + red[2] + red[3];
  const float sc = rsqrtf(tot * (1.0f / D_) + 1e-5f);
  const float4 gv = *(const float4*)(G + tid * 4);
  u16x4 o;
  o[0] = f2bf(xv.x * sc * gv.x);
  o[1] = f2bf(xv.y * sc * gv.y);
  o[2] = f2bf(xv.z * sc * gv.z);
  o[3] = f2bf(xv.w * sc * gv.w);
  *(u16x4*)(Out + (size_t)row * D_ + tid * 4) = o;
}

// ---------------------------------------------------------------------------
// RoPE on Q (scaled by 1/8, folding the attention softmax scale) and K,
// one dispatch. bf16 [4096][1024] viewed as uint pairs.
__global__ __launch_bounds__(256) void rope2_k(unsigned int* __restrict__ Qb,
                                               unsigned int* __restrict__ Kb,
                                               const int* __restrict__ pos) {
  int idx = blockIdx.x * 256 + threadIdx.x;  // < 2 * 4096*512
  unsigned int* buf = Qb;
  float scale = 0.125f;
  if (idx >= 2097152) { buf = Kb; scale = 1.f; idx -= 2097152; }
  const int row = idx >> 9, p = idx & 511;
  const int i = p & 31;  // pair index within head
  unsigned int v = buf[(size_t)row * 512 + p];
  const float xr = bf2f((u16)(v & 0xffffu));
  const float xi = bf2f((u16)(v >> 16));
  const float ang =
      (float)pos[row] * __expf(-(float)i * (9.210340371976184f / 32.0f));
  float sn, cs;
  sincosf(ang, &sn, &cs);
  const float orr = (xr * cs - xi * sn) * scale;
  const float oii = (xr * sn + xi * cs) * scale;
  buf[(size_t)row * 512 + p] =
      (unsigned int)f2bf(orr) | ((unsigned int)f2bf(oii) << 16);
}

// ---------------------------------------------------------------------------
// V [4096][1024] bf16 -> Vt [32 bh][64 dk][2048 s] bf16 (per-head transpose)
__global__ __launch_bounds__(256) void transpose_v(const u16* __restrict__ V,
                                                   u16* __restrict__ Vt) {
  __shared__ __align__(16) u16 tile[32][64];
  const int tid = threadIdx.x;
  const int s0 = blockIdx.x * 32, bh = blockIdx.y, b = bh >> 4, h = bh & 15;
  {
    const int sr = tid >> 3, c = tid & 7;
    *(u16x8*)&tile[sr][c * 8] =
        *(const u16x8*)(V + (size_t)(b * S_ + s0 + sr) * D_ + h * DK_ + c * 8);
  }
  __syncthreads();
  {
    const int dk = tid >> 2, cs = tid & 3;
    u16x8 vv;
#pragma unroll
    for (int j = 0; j < 8; ++j) vv[j] = tile[cs * 8 + j][dk];
    *(u16x8*)(Vt + (size_t)(bh * DK_ + dk) * S_ + s0 + cs * 8) = vv;
  }
}

// ---------------------------------------------------------------------------
// 256x256-tile 2-phase double-buffered GEMM (T3-minimum): C = A @ Bw^T.
// BK=32, 512 threads = 8 waves (2M x 4N), wave tile 128x64, LDS 64KB
// (2 blocks/CU). STAGE(next) issued BEFORE ds_read+MFMA; one barrier/K-step.
// EPI 0: bf16 store. EPI 2: swiglu vs aux bf16. EPI 3: QKV split store.
template <int EPI>
__global__ __launch_bounds__(512) void gemm256(const u16* __restrict__ A,
                                               const u16* __restrict__ Bw,
                                               void* __restrict__ Cout,
                                               const void* __restrict__ auxp,
                                               int N, int K) {
  __shared__ __align__(16) u16 As[2][256 * 32];
  __shared__ __align__(16) u16 Bs[2][256 * 32];
  const int tid = threadIdx.x, l = tid & 63, w = tid >> 6;
  const int gx = gridDim.x;
  const int nwg = gx * (int)gridDim.y;
  const int id = blockIdx.y * gx + blockIdx.x;
  const int swz = (id & 7) * (nwg >> 3) + (id >> 3);
  const int m0 = (swz / gx) * 256, n0 = (swz % gx) * 256;
  const int wm = (w >> 2) * 128, wn = (w & 3) * 64;
  const int lr = l & 15, lg = l >> 4;

  f32x4 acc[8][4] = {};

  // stage K-step k0 into buffer bf: A,B tiles 256x32 (16KB each, 1024 chunks)
  auto STAGE = [&](int bf, int k0) {
#pragma unroll
    for (int i = 0; i < 2; ++i) {
      const int slot = i * 512 + tid;       // 16B chunk id
      const int r = slot >> 2, ch = slot & 3;
      async_lds16(A + (size_t)(m0 + r) * K + k0 + ch * 8,
                  (char*)As[bf] + (i * 512 + w * 64) * 16);
      async_lds16(Bw + (size_t)(n0 + r) * K + k0 + ch * 8,
                  (char*)Bs[bf] + (i * 512 + w * 64) * 16);
    }
  };

  STAGE(0, 0);
  __syncthreads();
  int cur = 0;
  for (int k0 = 0; k0 < K; k0 += 32) {
    if (k0 + 32 < K) STAGE(cur ^ 1, k0 + 32);  // overlap with compute
    bf16x8 af[8], bfr[4];
#pragma unroll
    for (int i = 0; i < 8; ++i)
      af[i] = *(const bf16x8*)&As[cur][(wm + i * 16 + lr) * 32 + lg * 8];
#pragma unroll
    for (int j = 0; j < 4; ++j)
      bfr[j] = *(const bf16x8*)&Bs[cur][(wn + j * 16 + lr) * 32 + lg * 8];
    __builtin_amdgcn_s_setprio(1);
#pragma unroll
    for (int i = 0; i < 8; ++i)
#pragma unroll
      for (int j = 0; j < 4; ++j)
        acc[i][j] = __builtin_amdgcn_mfma_f32_16x16x32_bf16(af[i], bfr[j],
                                                            acc[i][j], 0, 0, 0);
    __builtin_amdgcn_s_setprio(0);
    __syncthreads();  // drains vmcnt(0): next tile staged + cur reusable
    cur ^= 1;
  }

#pragma unroll
  for (int i = 0; i < 8; ++i) {
#pragma unroll
    for (int j = 0; j < 4; ++j) {
#pragma unroll
      for (int t = 0; t < 4; ++t) {
        const int grow = m0 + wm + i * 16 + lg * 4 + t;
        const int gcol = n0 + wn + j * 16 + lr;
        const float v = acc[i][j][t];
        if (EPI == 0) {
          ((u16*)Cout)[(size_t)grow * N + gcol] = f2bf(v);
        } else if (EPI == 2) {
          const size_t idx = (size_t)grow * N + gcol;
          const float av = bf2f(((const u16*)auxp)[idx]);
          const float sw = av / (1.f + __expf(-av));
          ((u16*)Cout)[idx] = f2bf(sw * v);
        } else {
          u16* base = (u16*)Cout + (size_t)(gcol >> 10) * ((size_t)M_ * D_);
          base[(size_t)grow * D_ + (gcol & 1023)] = f2bf(v);
        }
      }
    }
  }
}

// ---------------------------------------------------------------------------
// 128x128 GEMM (kept for N=1024 shapes: WO, W2). EPI 1: f32 aux + acc store.
template <int EPI>
__global__ __launch_bounds__(256) void gemm_bt(const u16* __restrict__ A,
                                               const u16* __restrict__ Bw,
                                               void* __restrict__ Cout,
                                               const void* __restrict__ auxp,
                                               int N, int K) {
  __shared__ __align__(16) u16 As[128 * 32];
  __shared__ __align__(16) u16 Bs[128 * 32];
  const int tid = threadIdx.x;
  const int l = tid & 63, w = tid >> 6;
  const int gx = gridDim.x;
  const int nwg = gx * (int)gridDim.y;
  const int id = blockIdx.y * gx + blockIdx.x;
  const int swz = (id & 7) * (nwg >> 3) + (id >> 3);
  const int m0 = (swz / gx) * 128, n0 = (swz % gx) * 128;
  const int wm = (w >> 1) * 64, wn = (w & 1) * 64;
  const int lr = l & 15, lg = l >> 4;

  f32x4 acc[4][4] = {};
  const int sA0 = w * 128;

  for (int k0 = 0; k0 < K; k0 += 32) {
#pragma unroll
    for (int inst = 0; inst < 2; ++inst) {
      const int s = sA0 + inst * 64 + l;
      const int row = s >> 2, c = s & 3;
      async_lds16(A + (size_t)(m0 + row) * K + k0 + c * 8,
                  (char*)As + (sA0 + inst * 64) * 16);
      async_lds16(Bw + (size_t)(n0 + row) * K + k0 + c * 8,
                  (char*)Bs + (sA0 + inst * 64) * 16);
    }
    __syncthreads();
    bf16x8 af[4], bfr[4];
#pragma unroll
    for (int i = 0; i < 4; ++i)
      af[i] = *(const bf16x8*)&As[(wm + i * 16 + lr) * 32 + lg * 8];
#pragma unroll
    for (int j = 0; j < 4; ++j)
      bfr[j] = *(const bf16x8*)&Bs[(wn + j * 16 + lr) * 32 + lg * 8];
    __builtin_amdgcn_s_setprio(1);
#pragma unroll
    for (int i = 0; i < 4; ++i)
#pragma unroll
      for (int j = 0; j < 4; ++j)
        acc[i][j] = __builtin_amdgcn_mfma_f32_16x16x32_bf16(af[i], bfr[j],
                                                            acc[i][j], 0, 0, 0);
    __builtin_amdgcn_s_setprio(0);
    __syncthreads();
  }

#pragma unroll
  for (int i = 0; i < 4; ++i) {
#pragma unroll
    for (int j = 0; j < 4; ++j) {
#pragma unroll
      for (int t = 0; t < 4; ++t) {
        const int grow = m0 + wm + i * 16 + lg * 4 + t;
        const int gcol = n0 + wn + j * 16 + lr;
        const float v = acc[i][j][t];
        if (EPI == 0) {
          ((u16*)Cout)[(size_t)grow * N + gcol] = f2bf(v);
        } else if (EPI == 1) {
          const size_t idx = (size_t)grow * N + gcol;
          ((float*)Cout)[idx] = ((const float*)auxp)[idx] + v;
        }
      }
    }
  }
}

// ---------------------------------------------------------------------------
// Causal flash attention. Q pre-scaled by 1/8 in RoPE. KVBLK=64, dbuf LDS,
// XOR-swizzled K/V tiles, full/diagonal tile split, defer-max (THR=8).
__global__ __launch_bounds__(256) void attn_fwd(const u16* __restrict__ Q,
                                                const u16* __restrict__ K,
                                                const u16* __restrict__ Vt,
                                                u16* __restrict__ O) {
  __shared__ __align__(16) u16 Ks[2][64 * 64];
  __shared__ __align__(16) u16 Vs[2][64 * 64];
  __shared__ __align__(16) u16 Ps[4][16 * 72];
  const int tid = threadIdx.x, l = tid & 63, w = tid >> 6;
  const int lr = l & 15, lg = l >> 4;
  const int bid = blockIdx.x;
  const int xcd = bid & 7, i = bid >> 3;
  const int bh = xcd * 4 + (i >> 5);  // 4 heads per XCD
  const int qx = 31 - (i & 31);       // heavy first
  const int b = bh >> 4, h = bh & 15;
  const int q0w = qx * 64 + w * 16;

  const u16* Kb = K + (size_t)(b * S_) * D_ + h * DK_;
  const u16* Vb = Vt + (size_t)bh * DK_ * S_;

  bf16x8 aq[2];
  {
    const u16* qp = Q + (size_t)(b * S_ + q0w + lr) * D_ + h * DK_ + lg * 8;
    aq[0] = *(const bf16x8*)qp;
    aq[1] = *(const bf16x8*)(qp + 32);
  }
  f32x4 oacc[4] = {};
  float mrow[4], lrow[4];
#pragma unroll
  for (int t = 0; t < 4; ++t) { mrow[t] = -1e30f; lrow[t] = 0.f; }

  auto STAGE = [&](int bf, int t) {
#pragma unroll
    for (int inst = 0; inst < 2; ++inst) {
      const int s = (w * 2 + inst) * 64 + l;
      const int r = s >> 3, ch = s & 7;
      const int chs = ch ^ (r & 7);
      async_lds16(Kb + (size_t)(t * 64 + r) * D_ + chs * 8,
                  (char*)Ks[bf] + (w * 2 + inst) * 1024);
      async_lds16(Vb + (size_t)r * S_ + t * 64 + chs * 8,
                  (char*)Vs[bf] + (w * 2 + inst) * 1024);
    }
  };

  auto QKT = [&](int cur, f32x4* sf) {
    __builtin_amdgcn_s_setprio(1);
#pragma unroll
    for (int n = 0; n < 4; ++n) {
      const int kvr = n * 16 + lr;
      f32x4 z = {};
#pragma unroll
      for (int ss = 0; ss < 2; ++ss) {
        const int cw = ss * 4 + lg;
        bf16x8 bk = *(const bf16x8*)&Ks[cur][kvr * 64 + ((cw ^ (kvr & 7)) * 8)];
        z = __builtin_amdgcn_mfma_f32_16x16x32_bf16(aq[ss], bk, z, 0, 0, 0);
      }
      sf[n] = z;
    }
    __builtin_amdgcn_s_setprio(0);
  };

  auto PV = [&](int cur) {
    bf16x8 ap0 = *(const bf16x8*)&Ps[w][lr * 72 + lg * 8];
    bf16x8 ap1 = *(const bf16x8*)&Ps[w][lr * 72 + 32 + lg * 8];
    __builtin_amdgcn_s_setprio(1);
#pragma unroll
    for (int d = 0; d < 4; ++d) {
      const int row = d * 16 + lr;
      bf16x8 bv0 = *(const bf16x8*)&Vs[cur][row * 64 + ((lg ^ (row & 7)) * 8)];
      bf16x8 bv1 =
          *(const bf16x8*)&Vs[cur][row * 64 + (((4 + lg) ^ (row & 7)) * 8)];
      oacc[d] = __builtin_amdgcn_mfma_f32_16x16x32_bf16(ap0, bv0, oacc[d], 0, 0, 0);
      oacc[d] = __builtin_amdgcn_mfma_f32_16x16x32_bf16(ap1, bv1, oacc[d], 0, 0, 0);
    }
    __builtin_amdgcn_s_setprio(0);
  };

  STAGE(0, 0);
  __syncthreads();
  int cur = 0;
  // FULL tiles (kv strictly below all q rows of this wave): no causal mask.
  for (int it = 0; it < qx; ++it) {
    STAGE(cur ^ 1, it + 1);
    f32x4 sf[4];
    QKT(cur, sf);
    // defer-max: in-lane check only; reduce+rescale only when needed
    float fm[4];
    bool exc = false;
#pragma unroll
    for (int t = 0; t < 4; ++t) {
      fm[t] = fmaxf(fmaxf(sf[0][t], sf[1][t]), fmaxf(sf[2][t], sf[3][t]));
      exc |= fm[t] > mrow[t] + 8.f;
    }
    if (__any(exc)) {
#pragma unroll
      for (int t = 0; t < 4; ++t) {
        float mx = fm[t];
#pragma unroll
        for (int off = 1; off < 16; off <<= 1)
          mx = fmaxf(mx, __shfl_xor(mx, off));
        const float nm = fmaxf(mrow[t], mx);
        const float c = __expf(mrow[t] - nm);
        mrow[t] = nm;
        lrow[t] *= c;
#pragma unroll
        for (int d = 0; d < 4; ++d) oacc[d][t] *= c;
      }
    }
#pragma unroll
    for (int t = 0; t < 4; ++t) {
      float ps = 0.f;
#pragma unroll
      for (int n = 0; n < 4; ++n) {
        const float e = __expf(sf[n][t] - mrow[t]);
        ps += e;
        Ps[w][(lg * 4 + t) * 72 + n * 16 + lr] = f2bf(e);
      }
#pragma unroll
      for (int off = 1; off < 16; off <<= 1) ps += __shfl_xor(ps, off);
      lrow[t] += ps;
    }
    PV(cur);
    __syncthreads();
    cur ^= 1;
  }
  // DIAGONAL tile (it = qx): causal mask + always-rescale path.
  {
    const int kv0 = qx * 64;
    f32x4 sf[4];
    QKT(cur, sf);
#pragma unroll
    for (int t = 0; t < 4; ++t) {
      const int qrow = q0w + lg * 4 + t;
      float v[4];
#pragma unroll
      for (int n = 0; n < 4; ++n)
        v[n] = (kv0 + n * 16 + lr <= qrow) ? sf[n][t] : -1e30f;
      float mx = fmaxf(fmaxf(v[0], v[1]), fmaxf(v[2], v[3]));
#pragma unroll
      for (int off = 1; off < 16; off <<= 1) mx = fmaxf(mx, __shfl_xor(mx, off));
      const float nm = fmaxf(mrow[t], mx);
      float e[4], ps = 0.f;
#pragma unroll
      for (int n = 0; n < 4; ++n) { e[n] = __expf(v[n] - nm); ps += e[n]; }
#pragma unroll
      for (int off = 1; off < 16; off <<= 1) ps += __shfl_xor(ps, off);
      const float c = __expf(mrow[t] - nm);
      lrow[t] = lrow[t] * c + ps;
      mrow[t] = nm;
#pragma unroll
      for (int d = 0; d < 4; ++d) oacc[d][t] *= c;
#pragma unroll
      for (int n = 0; n < 4; ++n)
        Ps[w][(lg * 4 + t) * 72 + n * 16 + lr] = f2bf(e[n]);
    }
    PV(cur);
  }
#pragma unroll
  for (int d = 0; d < 4; ++d) {
#pragma unroll
    for (int t = 0; t < 4; ++t) {
      const size_t idx =
          (size_t)(b * S_ + q0w + lg * 4 + t) * D_ + h * DK_ + d * 16 + lr;
      O[idx] = f2bf(oacc[d][t] / lrow[t]);
    }
  }
}

// ---------------------------------------------------------------------------
extern "C" void kernel_launch(void* const* d_in, const int* in_sizes, int n_in,
                              void* d_out, int out_size, void* d_ws,
                              size_t ws_size, hipStream_t stream) {
  (void)in_sizes; (void)n_in; (void)out_size; (void)ws_size;
  const float* x = (const float*)d_in[0];
  const float* wq = (const float*)d_in[1];
  const float* wk = (const float*)d_in[2];
  const float* wv = (const float*)d_in[3];
  const float* wo = (const float*)d_in[4];
  const float* w1 = (const float*)d_in[5];
  const float* w2 = (const float*)d_in[6];
  const float* w3 = (const float*)d_in[7];
  const float* g1 = (const float*)d_in[8];
  const float* g2 = (const float*)d_in[9];
  const int* tp = (const int*)d_in[10];
  float* out = (float*)d_out;

  char* ws = (char*)d_ws;
  const size_t MB = 1024u * 1024u;
  u16* wqkvb = (u16*)(ws + 0 * MB);   // [3072][1024] = 6MB
  u16* wob = (u16*)(ws + 6 * MB);
  u16* w1b = (u16*)(ws + 8 * MB);
  u16* w2b = (u16*)(ws + 16 * MB);
  u16* w3b = (u16*)(ws + 24 * MB);
  u16* hb  = (u16*)(ws + 32 * MB);    // rmsnorm1 out; later attn-out
  float* yb = (float*)(ws + 40 * MB); // 16MB f32
  u16* h2b = (u16*)(ws + 56 * MB);
  u16* Qb  = (u16*)(ws + 64 * MB);    // Q/K/V contiguous (EPI3 split store)
  u16* Kb  = (u16*)(ws + 72 * MB);
  u16* Vb  = (u16*)(ws + 80 * MB);
  u16* Vtb = (u16*)(ws + 88 * MB);
  u16* ab  = (u16*)(ws + 64 * MB);    // 32MB, reuses Q/K/V/Vt after attention
  u16* ffb = (u16*)(ws + 96 * MB);    // 32MB
  u16* aob = hb;

  f2b_all<<<16384, 256, 0, stream>>>(wq, wk, wv, wo, w1, w2, w3, wqkvb, wob,
                                     w1b, w2b, w3b);

  rmsnorm_k<<<4096, 256, 0, stream>>>(x, g1, hb);

  // fused QKV projection: N=3072, 256^2 tiles, split-stored into Qb/Kb/Vb
  gemm256<3><<<dim3(12, 16), 512, 0, stream>>>(hb, wqkvb, Qb, nullptr, 3072,
                                               1024);

  rope2_k<<<16384, 256, 0, stream>>>((unsigned int*)Qb, (unsigned int*)Kb, tp);
  transpose_v<<<dim3(64, 32), 256, 0, stream>>>(Vb, Vtb);

  attn_fwd<<<1024, 256, 0, stream>>>(Qb, Kb, Vtb, aob);

  gemm_bt<1><<<dim3(8, 32), 256, 0, stream>>>(aob, wob, yb, x, 1024, 1024);
  rmsnorm_k<<<4096, 256, 0, stream>>>(yb, g2, h2b);

  gemm256<0><<<dim3(16, 16), 512, 0, stream>>>(h2b, w1b, ab, nullptr, 4096,
                                               1024);
  gemm256<2><<<dim3(16, 16), 512, 0, stream>>>(h2b, w3b, ffb, ab, 4096, 1024);
  gemm_bt<1><<<dim3(8, 32), 256, 0, stream>>>(ffb, w2b, out, yb, 1024, 4096);
}

// Round 5
// 355.220 us; speedup vs baseline: 1.5505x; 1.0215x over previous
//
#include <hip/hip_runtime.h>
#include <hip/hip_bf16.h>

#define B_ 2
#define S_ 2048
#define D_ 1024
#define H_ 16
#define DK_ 64
#define FF_ 4096
#define M_ (B_ * S_)  // 4096 rows

typedef unsigned short u16;
typedef __bf16 bf16x8 __attribute__((ext_vector_type(8)));
typedef float f32x4 __attribute__((ext_vector_type(4)));
typedef u16 u16x4 __attribute__((ext_vector_type(4)));
typedef u16 u16x8 __attribute__((ext_vector_type(8)));

__device__ __forceinline__ u16 f2bf(float f) {
  __bf16 b = (__bf16)f;
  return __builtin_bit_cast(u16, b);
}
__device__ __forceinline__ float bf2f(u16 u) {
  __bf16 b = __builtin_bit_cast(__bf16, u);
  return (float)b;
}

// async global->LDS, 16B per lane. LDS dest is wave-uniform base + lane*16.
__device__ __forceinline__ void async_lds16(const void* g, void* l) {
  __builtin_amdgcn_global_load_lds(
      (const __attribute__((address_space(1))) unsigned int*)g,
      (__attribute__((address_space(3))) unsigned int*)l, 16, 0, 0);
}

// ---------------------------------------------------------------------------
// All weights f32 -> bf16 in ONE dispatch. 16M f32 elems = 4M float4.
__global__ __launch_bounds__(256) void f2b_all(
    const float* __restrict__ wq, const float* __restrict__ wk,
    const float* __restrict__ wv, const float* __restrict__ wo,
    const float* __restrict__ w1, const float* __restrict__ w2,
    const float* __restrict__ w3, u16* __restrict__ wqkvb,
    u16* __restrict__ wob, u16* __restrict__ w1b, u16* __restrict__ w2b,
    u16* __restrict__ w3b) {
  int i4 = blockIdx.x * 256 + threadIdx.x;  // < 4M
  const float* src;
  u16* dst;
  int off;
  if (i4 < 262144) { src = wq; dst = wqkvb; off = i4; }
  else if (i4 < 524288) { src = wk; dst = wqkvb + 1048576; off = i4 - 262144; }
  else if (i4 < 786432) { src = wv; dst = wqkvb + 2097152; off = i4 - 524288; }
  else if (i4 < 1048576) { src = wo; dst = wob; off = i4 - 786432; }
  else if (i4 < 2097152) { src = w1; dst = w1b; off = i4 - 1048576; }
  else if (i4 < 3145728) { src = w2; dst = w2b; off = i4 - 2097152; }
  else { src = w3; dst = w3b; off = i4 - 3145728; }
  float4 v = ((const float4*)src)[off];
  u16x4 o;
  o[0] = f2bf(v.x); o[1] = f2bf(v.y); o[2] = f2bf(v.z); o[3] = f2bf(v.w);
  *(u16x4*)(dst + (size_t)off * 4) = o;
}

// ---------------------------------------------------------------------------
// RMSNorm: f32 [rows][1024] -> bf16, block per row, 256 threads * 4 cols
__global__ __launch_bounds__(256) void rmsnorm_k(const float* __restrict__ X,
                                                 const float* __restrict__ G,
                                                 u16* __restrict__ Out) {
  const int row = blockIdx.x, tid = threadIdx.x;
  const float4 xv = *(const float4*)(X + (size_t)row * D_ + tid * 4);
  float ss = xv.x * xv.x + xv.y * xv.y + xv.z * xv.z + xv.w * xv.w;
#pragma unroll
  for (int off = 1; off < 64; off <<= 1) ss += __shfl_xor(ss, off);
  __shared__ float red[4];
  if ((tid & 63) == 0) red[tid >> 6] = ss;
  __syncthreads();
  const float tot = red[0] + red[1] + red[2] + red[3];
  const float sc = rsqrtf(tot * (1.0f / D_) + 1e-5f);
  const float4 gv = *(const float4*)(G + tid * 4);
  u16x4 o;
  o[0] = f2bf(xv.x * sc * gv.x);
  o[1] = f2bf(xv.y * sc * gv.y);
  o[2] = f2bf(xv.z * sc * gv.z);
  o[3] = f2bf(xv.w * sc * gv.w);
  *(u16x4*)(Out + (size_t)row * D_ + tid * 4) = o;
}

// ---------------------------------------------------------------------------
// RoPE on Q (scaled by 1/8, folding the attention softmax scale) and K,
// one dispatch. bf16 [4096][1024] viewed as uint pairs.
__global__ __launch_bounds__(256) void rope2_k(unsigned int* __restrict__ Qb,
                                               unsigned int* __restrict__ Kb,
                                               const int* __restrict__ pos) {
  int idx = blockIdx.x * 256 + threadIdx.x;  // < 2 * 4096*512
  unsigned int* buf = Qb;
  float scale = 0.125f;
  if (idx >= 2097152) { buf = Kb; scale = 1.f; idx -= 2097152; }
  const int row = idx >> 9, p = idx & 511;
  const int i = p & 31;  // pair index within head
  unsigned int v = buf[(size_t)row * 512 + p];
  const float xr = bf2f((u16)(v & 0xffffu));
  const float xi = bf2f((u16)(v >> 16));
  const float ang =
      (float)pos[row] * __expf(-(float)i * (9.210340371976184f / 32.0f));
  float sn, cs;
  sincosf(ang, &sn, &cs);
  const float orr = (xr * cs - xi * sn) * scale;
  const float oii = (xr * sn + xi * cs) * scale;
  buf[(size_t)row * 512 + p] =
      (unsigned int)f2bf(orr) | ((unsigned int)f2bf(oii) << 16);
}

// ---------------------------------------------------------------------------
// V [4096][1024] bf16 -> Vt [32 bh][64 dk][2048 s] bf16 (per-head transpose)
__global__ __launch_bounds__(256) void transpose_v(const u16* __restrict__ V,
                                                   u16* __restrict__ Vt) {
  __shared__ __align__(16) u16 tile[32][64];
  const int tid = threadIdx.x;
  const int s0 = blockIdx.x * 32, bh = blockIdx.y, b = bh >> 4, h = bh & 15;
  {
    const int sr = tid >> 3, c = tid & 7;
    *(u16x8*)&tile[sr][c * 8] =
        *(const u16x8*)(V + (size_t)(b * S_ + s0 + sr) * D_ + h * DK_ + c * 8);
  }
  __syncthreads();
  {
    const int dk = tid >> 2, cs = tid & 3;
    u16x8 vv;
#pragma unroll
    for (int j = 0; j < 8; ++j) vv[j] = tile[cs * 8 + j][dk];
    *(u16x8*)(Vt + (size_t)(bh * DK_ + dk) * S_ + s0 + cs * 8) = vv;
  }
}

// ---------------------------------------------------------------------------
// Unified 2-phase double-buffered GEMM: C[M,N] = A[M,K] @ Bw[N,K]^T.
// 512 threads = 8 waves (2M x 4N), wave tile (BM/2)x(BN/4), BK=32.
// STAGE(next) issued BEFORE ds_read+MFMA; ONE barrier per K-step (drains
// vmcnt -> next tile staged + cur buffer reusable). setprio around MFMA.
// XCD-chunked bijective block swizzle (all grids have nwg % 8 == 0).
// EPI 0: bf16 store. EPI 1: f32 store of aux(f32)+acc. EPI 2: swiglu
//        bf16(silu(aux)*acc). EPI 3: QKV split store (regions 8MB apart).
template <int BM, int BN, int EPI>
__global__ __launch_bounds__(512) void gemm2ph(const u16* __restrict__ A,
                                               const u16* __restrict__ Bw,
                                               void* __restrict__ Cout,
                                               const void* __restrict__ auxp,
                                               int N, int K) {
  constexpr int ACH = BM * 4;              // A 16B-chunks per K-step
  constexpr int TCH = (BM + BN) * 4;       // total chunks per K-step
  constexpr int MR = BM / 32, NR = BN / 64;
  __shared__ __align__(16) u16 As[2][BM * 32];
  __shared__ __align__(16) u16 Bs[2][BN * 32];
  const int tid = threadIdx.x, l = tid & 63, w = tid >> 6;
  const int gx = gridDim.x;
  const int nwg = gx * (int)gridDim.y;
  const int id = blockIdx.y * gx + blockIdx.x;
  const int swz = (id & 7) * (nwg >> 3) + (id >> 3);
  const int m0 = (swz / gx) * BM, n0 = (swz % gx) * BN;
  const int wm = (w >> 2) * (BM / 2), wn = (w & 3) * (BN / 4);
  const int lr = l & 15, lg = l >> 4;

  f32x4 acc[MR][NR] = {};

  auto STAGE = [&](int bf, int k0) {
#pragma unroll
    for (int i = 0; i < TCH / 512; ++i) {
      const int s = i * 512 + tid;            // chunk id
      const int base = i * 512 + w * 64;      // wave-uniform chunk base
      if (base < ACH) {                       // wave-uniform branch (ACH%64==0)
        const int r = s >> 2, ch = s & 3;
        async_lds16(A + (size_t)(m0 + r) * K + k0 + ch * 8,
                    (char*)As[bf] + base * 16);
      } else {
        const int s2 = s - ACH;
        const int r = s2 >> 2, ch = s2 & 3;
        async_lds16(Bw + (size_t)(n0 + r) * K + k0 + ch * 8,
                    (char*)Bs[bf] + (base - ACH) * 16);
      }
    }
  };

  STAGE(0, 0);
  __syncthreads();
  int cur = 0;
  for (int k0 = 0; k0 < K; k0 += 32) {
    if (k0 + 32 < K) STAGE(cur ^ 1, k0 + 32);  // overlap with compute
    bf16x8 af[MR], bfr[NR];
#pragma unroll
    for (int i = 0; i < MR; ++i)
      af[i] = *(const bf16x8*)&As[cur][(wm + i * 16 + lr) * 32 + lg * 8];
#pragma unroll
    for (int j = 0; j < NR; ++j)
      bfr[j] = *(const bf16x8*)&Bs[cur][(wn + j * 16 + lr) * 32 + lg * 8];
    __builtin_amdgcn_s_setprio(1);
#pragma unroll
    for (int i = 0; i < MR; ++i)
#pragma unroll
      for (int j = 0; j < NR; ++j)
        acc[i][j] = __builtin_amdgcn_mfma_f32_16x16x32_bf16(af[i], bfr[j],
                                                            acc[i][j], 0, 0, 0);
    __builtin_amdgcn_s_setprio(0);
    __syncthreads();  // drains vmcnt(0): next tile staged + cur reusable
    cur ^= 1;
  }

  // epilogue: C/D layout col = l&15, row = (l>>4)*4 + t  [m89-verified]
#pragma unroll
  for (int i = 0; i < MR; ++i) {
#pragma unroll
    for (int j = 0; j < NR; ++j) {
#pragma unroll
      for (int t = 0; t < 4; ++t) {
        const int grow = m0 + wm + i * 16 + lg * 4 + t;
        const int gcol = n0 + wn + j * 16 + lr;
        const float v = acc[i][j][t];
        if (EPI == 0) {
          ((u16*)Cout)[(size_t)grow * N + gcol] = f2bf(v);
        } else if (EPI == 1) {
          const size_t idx = (size_t)grow * N + gcol;
          ((float*)Cout)[idx] = ((const float*)auxp)[idx] + v;
        } else if (EPI == 2) {
          const size_t idx = (size_t)grow * N + gcol;
          const float av = bf2f(((const u16*)auxp)[idx]);
          const float sw = av / (1.f + __expf(-av));
          ((u16*)Cout)[idx] = f2bf(sw * v);
        } else {
          u16* base = (u16*)Cout + (size_t)(gcol >> 10) * ((size_t)M_ * D_);
          base[(size_t)grow * D_ + (gcol & 1023)] = f2bf(v);
        }
      }
    }
  }
}

// ---------------------------------------------------------------------------
// Causal flash attention. Q pre-scaled by 1/8 in RoPE. KVBLK=64, dbuf LDS,
// XOR-swizzled K/V tiles, full/diagonal tile split, defer-max (THR=8).
__global__ __launch_bounds__(256) void attn_fwd(const u16* __restrict__ Q,
                                                const u16* __restrict__ K,
                                                const u16* __restrict__ Vt,
                                                u16* __restrict__ O) {
  __shared__ __align__(16) u16 Ks[2][64 * 64];
  __shared__ __align__(16) u16 Vs[2][64 * 64];
  __shared__ __align__(16) u16 Ps[4][16 * 72];
  const int tid = threadIdx.x, l = tid & 63, w = tid >> 6;
  const int lr = l & 15, lg = l >> 4;
  const int bid = blockIdx.x;
  const int xcd = bid & 7, i = bid >> 3;
  const int bh = xcd * 4 + (i >> 5);  // 4 heads per XCD
  const int qx = 31 - (i & 31);       // heavy first
  const int b = bh >> 4, h = bh & 15;
  const int q0w = qx * 64 + w * 16;

  const u16* Kb = K + (size_t)(b * S_) * D_ + h * DK_;
  const u16* Vb = Vt + (size_t)bh * DK_ * S_;

  bf16x8 aq[2];
  {
    const u16* qp = Q + (size_t)(b * S_ + q0w + lr) * D_ + h * DK_ + lg * 8;
    aq[0] = *(const bf16x8*)qp;
    aq[1] = *(const bf16x8*)(qp + 32);
  }
  f32x4 oacc[4] = {};
  float mrow[4], lrow[4];
#pragma unroll
  for (int t = 0; t < 4; ++t) { mrow[t] = -1e30f; lrow[t] = 0.f; }

  auto STAGE = [&](int bf, int t) {
#pragma unroll
    for (int inst = 0; inst < 2; ++inst) {
      const int s = (w * 2 + inst) * 64 + l;
      const int r = s >> 3, ch = s & 7;
      const int chs = ch ^ (r & 7);
      async_lds16(Kb + (size_t)(t * 64 + r) * D_ + chs * 8,
                  (char*)Ks[bf] + (w * 2 + inst) * 1024);
      async_lds16(Vb + (size_t)r * S_ + t * 64 + chs * 8,
                  (char*)Vs[bf] + (w * 2 + inst) * 1024);
    }
  };

  auto QKT = [&](int cur, f32x4* sf) {
    __builtin_amdgcn_s_setprio(1);
#pragma unroll
    for (int n = 0; n < 4; ++n) {
      const int kvr = n * 16 + lr;
      f32x4 z = {};
#pragma unroll
      for (int ss = 0; ss < 2; ++ss) {
        const int cw = ss * 4 + lg;
        bf16x8 bk = *(const bf16x8*)&Ks[cur][kvr * 64 + ((cw ^ (kvr & 7)) * 8)];
        z = __builtin_amdgcn_mfma_f32_16x16x32_bf16(aq[ss], bk, z, 0, 0, 0);
      }
      sf[n] = z;
    }
    __builtin_amdgcn_s_setprio(0);
  };

  auto PV = [&](int cur) {
    bf16x8 ap0 = *(const bf16x8*)&Ps[w][lr * 72 + lg * 8];
    bf16x8 ap1 = *(const bf16x8*)&Ps[w][lr * 72 + 32 + lg * 8];
    __builtin_amdgcn_s_setprio(1);
#pragma unroll
    for (int d = 0; d < 4; ++d) {
      const int row = d * 16 + lr;
      bf16x8 bv0 = *(const bf16x8*)&Vs[cur][row * 64 + ((lg ^ (row & 7)) * 8)];
      bf16x8 bv1 =
          *(const bf16x8*)&Vs[cur][row * 64 + (((4 + lg) ^ (row & 7)) * 8)];
      oacc[d] = __builtin_amdgcn_mfma_f32_16x16x32_bf16(ap0, bv0, oacc[d], 0, 0, 0);
      oacc[d] = __builtin_amdgcn_mfma_f32_16x16x32_bf16(ap1, bv1, oacc[d], 0, 0, 0);
    }
    __builtin_amdgcn_s_setprio(0);
  };

  STAGE(0, 0);
  __syncthreads();
  int cur = 0;
  // FULL tiles (kv strictly below all q rows of this wave): no causal mask.
  for (int it = 0; it < qx; ++it) {
    STAGE(cur ^ 1, it + 1);
    f32x4 sf[4];
    QKT(cur, sf);
    // defer-max: in-lane check only; reduce+rescale only when needed
    float fm[4];
    bool exc = false;
#pragma unroll
    for (int t = 0; t < 4; ++t) {
      fm[t] = fmaxf(fmaxf(sf[0][t], sf[1][t]), fmaxf(sf[2][t], sf[3][t]));
      exc |= fm[t] > mrow[t] + 8.f;
    }
    if (__any(exc)) {
#pragma unroll
      for (int t = 0; t < 4; ++t) {
        float mx = fm[t];
#pragma unroll
        for (int off = 1; off < 16; off <<= 1)
          mx = fmaxf(mx, __shfl_xor(mx, off));
        const float nm = fmaxf(mrow[t], mx);
        const float c = __expf(mrow[t] - nm);
        mrow[t] = nm;
        lrow[t] *= c;
#pragma unroll
        for (int d = 0; d < 4; ++d) oacc[d][t] *= c;
      }
    }
#pragma unroll
    for (int t = 0; t < 4; ++t) {
      float ps = 0.f;
#pragma unroll
      for (int n = 0; n < 4; ++n) {
        const float e = __expf(sf[n][t] - mrow[t]);
        ps += e;
        Ps[w][(lg * 4 + t) * 72 + n * 16 + lr] = f2bf(e);
      }
#pragma unroll
      for (int off = 1; off < 16; off <<= 1) ps += __shfl_xor(ps, off);
      lrow[t] += ps;
    }
    PV(cur);
    __syncthreads();
    cur ^= 1;
  }
  // DIAGONAL tile (it = qx): causal mask + always-rescale path.
  {
    const int kv0 = qx * 64;
    f32x4 sf[4];
    QKT(cur, sf);
#pragma unroll
    for (int t = 0; t < 4; ++t) {
      const int qrow = q0w + lg * 4 + t;
      float v[4];
#pragma unroll
      for (int n = 0; n < 4; ++n)
        v[n] = (kv0 + n * 16 + lr <= qrow) ? sf[n][t] : -1e30f;
      float mx = fmaxf(fmaxf(v[0], v[1]), fmaxf(v[2], v[3]));
#pragma unroll
      for (int off = 1; off < 16; off <<= 1) mx = fmaxf(mx, __shfl_xor(mx, off));
      const float nm = fmaxf(mrow[t], mx);
      float e[4], ps = 0.f;
#pragma unroll
      for (int n = 0; n < 4; ++n) { e[n] = __expf(v[n] - nm); ps += e[n]; }
#pragma unroll
      for (int off = 1; off < 16; off <<= 1) ps += __shfl_xor(ps, off);
      const float c = __expf(mrow[t] - nm);
      lrow[t] = lrow[t] * c + ps;
      mrow[t] = nm;
#pragma unroll
      for (int d = 0; d < 4; ++d) oacc[d][t] *= c;
#pragma unroll
      for (int n = 0; n < 4; ++n)
        Ps[w][(lg * 4 + t) * 72 + n * 16 + lr] = f2bf(e[n]);
    }
    PV(cur);
  }
#pragma unroll
  for (int d = 0; d < 4; ++d) {
#pragma unroll
    for (int t = 0; t < 4; ++t) {
      const size_t idx =
          (size_t)(b * S_ + q0w + lg * 4 + t) * D_ + h * DK_ + d * 16 + lr;
      O[idx] = f2bf(oacc[d][t] / lrow[t]);
    }
  }
}

// ---------------------------------------------------------------------------
extern "C" void kernel_launch(void* const* d_in, const int* in_sizes, int n_in,
                              void* d_out, int out_size, void* d_ws,
                              size_t ws_size, hipStream_t stream) {
  (void)in_sizes; (void)n_in; (void)out_size; (void)ws_size;
  const float* x = (const float*)d_in[0];
  const float* wq = (const float*)d_in[1];
  const float* wk = (const float*)d_in[2];
  const float* wv = (const float*)d_in[3];
  const float* wo = (const float*)d_in[4];
  const float* w1 = (const float*)d_in[5];
  const float* w2 = (const float*)d_in[6];
  const float* w3 = (const float*)d_in[7];
  const float* g1 = (const float*)d_in[8];
  const float* g2 = (const float*)d_in[9];
  const int* tp = (const int*)d_in[10];
  float* out = (float*)d_out;

  char* ws = (char*)d_ws;
  const size_t MB = 1024u * 1024u;
  u16* wqkvb = (u16*)(ws + 0 * MB);   // [3072][1024] = 6MB
  u16* wob = (u16*)(ws + 6 * MB);
  u16* w1b = (u16*)(ws + 8 * MB);
  u16* w2b = (u16*)(ws + 16 * MB);
  u16* w3b = (u16*)(ws + 24 * MB);
  u16* hb  = (u16*)(ws + 32 * MB);    // rmsnorm1 out; later attn-out
  float* yb = (float*)(ws + 40 * MB); // 16MB f32
  u16* h2b = (u16*)(ws + 56 * MB);
  u16* Qb  = (u16*)(ws + 64 * MB);    // Q/K/V contiguous (EPI3 split store)
  u16* Kb  = (u16*)(ws + 72 * MB);
  u16* Vb  = (u16*)(ws + 80 * MB);
  u16* Vtb = (u16*)(ws + 88 * MB);
  u16* ab  = (u16*)(ws + 64 * MB);    // 32MB, reuses Q/K/V/Vt after attention
  u16* ffb = (u16*)(ws + 96 * MB);    // 32MB
  u16* aob = hb;

  f2b_all<<<16384, 256, 0, stream>>>(wq, wk, wv, wo, w1, w2, w3, wqkvb, wob,
                                     w1b, w2b, w3b);

  rmsnorm_k<<<4096, 256, 0, stream>>>(x, g1, hb);

  // fused QKV projection: N=3072, 256^2 tiles, split-stored into Qb/Kb/Vb
  gemm2ph<256, 256, 3><<<dim3(12, 16), 512, 0, stream>>>(hb, wqkvb, Qb,
                                                         nullptr, 3072, 1024);

  rope2_k<<<16384, 256, 0, stream>>>((unsigned int*)Qb, (unsigned int*)Kb, tp);
  transpose_v<<<dim3(64, 32), 256, 0, stream>>>(Vb, Vtb);

  attn_fwd<<<1024, 256, 0, stream>>>(Qb, Kb, Vtb, aob);

  // WO: 128^2 tiles -> 256 blocks x 8 waves (2 waves/SIMD) + dbuf
  gemm2ph<128, 128, 1><<<dim3(8, 32), 512, 0, stream>>>(aob, wob, yb, x, 1024,
                                                        1024);
  rmsnorm_k<<<4096, 256, 0, stream>>>(yb, g2, h2b);

  gemm2ph<256, 256, 0><<<dim3(16, 16), 512, 0, stream>>>(h2b, w1b, ab, nullptr,
                                                         4096, 1024);
  gemm2ph<256, 256, 2><<<dim3(16, 16), 512, 0, stream>>>(h2b, w3b, ffb, ab,
                                                         4096, 1024);
  gemm2ph<128, 128, 1><<<dim3(8, 32), 512, 0, stream>>>(ffb, w2b, out, yb,
                                                        1024, 4096);
}

// Round 6
// 303.768 us; speedup vs baseline: 1.8132x; 1.1694x over previous
//
#include <hip/hip_runtime.h>
#include <hip/hip_bf16.h>

#define B_ 2
#define S_ 2048
#define D_ 1024
#define H_ 16
#define DK_ 64
#define FF_ 4096
#define M_ (B_ * S_)  // 4096 rows

typedef unsigned short u16;
typedef __bf16 bf16x8 __attribute__((ext_vector_type(8)));
typedef float f32x4 __attribute__((ext_vector_type(4)));
typedef u16 u16x4 __attribute__((ext_vector_type(4)));
typedef u16 u16x8 __attribute__((ext_vector_type(8)));

__device__ __forceinline__ u16 f2bf(float f) {
  __bf16 b = (__bf16)f;
  return __builtin_bit_cast(u16, b);
}
__device__ __forceinline__ float bf2f(u16 u) {
  __bf16 b = __builtin_bit_cast(__bf16, u);
  return (float)b;
}

// async global->LDS, 16B per lane. LDS dest is wave-uniform base + lane*16.
__device__ __forceinline__ void async_lds16(const void* g, void* l) {
  __builtin_amdgcn_global_load_lds(
      (const __attribute__((address_space(1))) unsigned int*)g,
      (__attribute__((address_space(3))) unsigned int*)l, 16, 0, 0);
}

// ---------------------------------------------------------------------------
// All weights f32 -> bf16 in ONE dispatch. 16M f32 elems = 4M float4.
__global__ __launch_bounds__(256) void f2b_all(
    const float* __restrict__ wq, const float* __restrict__ wk,
    const float* __restrict__ wv, const float* __restrict__ wo,
    const float* __restrict__ w1, const float* __restrict__ w2,
    const float* __restrict__ w3, u16* __restrict__ wqkvb,
    u16* __restrict__ wob, u16* __restrict__ w1b, u16* __restrict__ w2b,
    u16* __restrict__ w3b) {
  int i4 = blockIdx.x * 256 + threadIdx.x;  // < 4M
  const float* src;
  u16* dst;
  int off;
  if (i4 < 262144) { src = wq; dst = wqkvb; off = i4; }
  else if (i4 < 524288) { src = wk; dst = wqkvb + 1048576; off = i4 - 262144; }
  else if (i4 < 786432) { src = wv; dst = wqkvb + 2097152; off = i4 - 524288; }
  else if (i4 < 1048576) { src = wo; dst = wob; off = i4 - 786432; }
  else if (i4 < 2097152) { src = w1; dst = w1b; off = i4 - 1048576; }
  else if (i4 < 3145728) { src = w2; dst = w2b; off = i4 - 2097152; }
  else { src = w3; dst = w3b; off = i4 - 3145728; }
  float4 v = ((const float4*)src)[off];
  u16x4 o;
  o[0] = f2bf(v.x); o[1] = f2bf(v.y); o[2] = f2bf(v.z); o[3] = f2bf(v.w);
  *(u16x4*)(dst + (size_t)off * 4) = o;
}

// ---------------------------------------------------------------------------
// RMSNorm: f32 [rows][1024] -> bf16, block per row, 256 threads * 4 cols
__global__ __launch_bounds__(256) void rmsnorm_k(const float* __restrict__ X,
                                                 const float* __restrict__ G,
                                                 u16* __restrict__ Out) {
  const int row = blockIdx.x, tid = threadIdx.x;
  const float4 xv = *(const float4*)(X + (size_t)row * D_ + tid * 4);
  float ss = xv.x * xv.x + xv.y * xv.y + xv.z * xv.z + xv.w * xv.w;
#pragma unroll
  for (int off = 1; off < 64; off <<= 1) ss += __shfl_xor(ss, off);
  __shared__ float red[4];
  if ((tid & 63) == 0) red[tid >> 6] = ss;
  __syncthreads();
  const float tot = red[0] + red[1] + red[2] + red[3];
  const float sc = rsqrtf(tot * (1.0f / D_) + 1e-5f);
  const float4 gv = *(const float4*)(G + tid * 4);
  u16x4 o;
  o[0] = f2bf(xv.x * sc * gv.x);
  o[1] = f2bf(xv.y * sc * gv.y);
  o[2] = f2bf(xv.z * sc * gv.z);
  o[3] = f2bf(xv.w * sc * gv.w);
  *(u16x4*)(Out + (size_t)row * D_ + tid * 4) = o;
}

// ---------------------------------------------------------------------------
// RoPE on Q (scaled by 1/8, folding the attention softmax scale) and K,
// one dispatch. bf16 [4096][1024] viewed as uint pairs.
__global__ __launch_bounds__(256) void rope2_k(unsigned int* __restrict__ Qb,
                                               unsigned int* __restrict__ Kb,
                                               const int* __restrict__ pos) {
  int idx = blockIdx.x * 256 + threadIdx.x;  // < 2 * 4096*512
  unsigned int* buf = Qb;
  float scale = 0.125f;
  if (idx >= 2097152) { buf = Kb; scale = 1.f; idx -= 2097152; }
  const int row = idx >> 9, p = idx & 511;
  const int i = p & 31;  // pair index within head
  unsigned int v = buf[(size_t)row * 512 + p];
  const float xr = bf2f((u16)(v & 0xffffu));
  const float xi = bf2f((u16)(v >> 16));
  const float ang =
      (float)pos[row] * __expf(-(float)i * (9.210340371976184f / 32.0f));
  float sn, cs;
  sincosf(ang, &sn, &cs);
  const float orr = (xr * cs - xi * sn) * scale;
  const float oii = (xr * sn + xi * cs) * scale;
  buf[(size_t)row * 512 + p] =
      (unsigned int)f2bf(orr) | ((unsigned int)f2bf(oii) << 16);
}

// ---------------------------------------------------------------------------
// V [4096][1024] bf16 -> Vt [32 bh][64 dk][2048 s] bf16 (per-head transpose)
__global__ __launch_bounds__(256) void transpose_v(const u16* __restrict__ V,
                                                   u16* __restrict__ Vt) {
  __shared__ __align__(16) u16 tile[32][64];
  const int tid = threadIdx.x;
  const int s0 = blockIdx.x * 32, bh = blockIdx.y, b = bh >> 4, h = bh & 15;
  {
    const int sr = tid >> 3, c = tid & 7;
    *(u16x8*)&tile[sr][c * 8] =
        *(const u16x8*)(V + (size_t)(b * S_ + s0 + sr) * D_ + h * DK_ + c * 8);
  }
  __syncthreads();
  {
    const int dk = tid >> 2, cs = tid & 3;
    u16x8 vv;
#pragma unroll
    for (int j = 0; j < 8; ++j) vv[j] = tile[cs * 8 + j][dk];
    *(u16x8*)(Vt + (size_t)(bh * DK_ + dk) * S_ + s0 + cs * 8) = vv;
  }
}

// ---------------------------------------------------------------------------
// Unified 2-phase double-buffered GEMM: C[M,N] = A[M,K] @ Bw[N,K]^T.
// 512 threads = 8 waves (2M x 4N), wave tile (BM/2)x(BN/4), K-step = BK.
// T2 XOR chunk-swizzle: stage reads pre-swizzled global source into linear
// LDS; ds_read applies the same (row&7) XOR on the 16B-chunk index ->
// conflict-free b128 reads. STAGE(next) issued BEFORE compute; ONE barrier
// per K-step. setprio around each MFMA cluster. XCD-chunked block swizzle.
// EPI 0: bf16 store. EPI 1: f32 store of aux(f32)+acc. EPI 2: swiglu
//        bf16(silu(aux)*acc). EPI 3: QKV split store (regions 8MB apart).
template <int BM, int BN, int BK, int EPI>
__global__ __launch_bounds__(512) void gemm2ph(const u16* __restrict__ A,
                                               const u16* __restrict__ Bw,
                                               void* __restrict__ Cout,
                                               const void* __restrict__ auxp,
                                               int N, int K) {
  constexpr int CPR = BK / 8;              // 16B chunks per row
  constexpr int ACH = BM * CPR;            // A chunks per K-step
  constexpr int TCH = (BM + BN) * CPR;     // total chunks per K-step
  constexpr int MR = BM / 32, NR = BN / 64;
  __shared__ __align__(16) u16 As[2][BM * BK];
  __shared__ __align__(16) u16 Bs[2][BN * BK];
  const int tid = threadIdx.x, l = tid & 63, w = tid >> 6;
  const int gx = gridDim.x;
  const int nwg = gx * (int)gridDim.y;
  const int id = blockIdx.y * gx + blockIdx.x;
  const int swz = (id & 7) * (nwg >> 3) + (id >> 3);
  const int m0 = (swz / gx) * BM, n0 = (swz % gx) * BN;
  const int wm = (w >> 2) * (BM / 2), wn = (w & 3) * (BN / 4);
  const int lr = l & 15, lg = l >> 4;

  f32x4 acc[MR][NR] = {};

  auto STAGE = [&](int bf, int k0) {
#pragma unroll
    for (int i = 0; i < TCH / 512; ++i) {
      const int s = i * 512 + tid;            // chunk id
      const int base = i * 512 + w * 64;      // wave-uniform chunk base
      if (base < ACH) {                       // compile-time-ish branch
        const int r = s / CPR, ch = s % CPR;
        async_lds16(A + (size_t)(m0 + r) * K + k0 + ((ch ^ (r & 7)) * 8),
                    (char*)As[bf] + base * 16);
      } else {
        const int s2 = s - ACH;
        const int r = s2 / CPR, ch = s2 % CPR;
        async_lds16(Bw + (size_t)(n0 + r) * K + k0 + ((ch ^ (r & 7)) * 8),
                    (char*)Bs[bf] + (base - ACH) * 16);
      }
    }
  };

  STAGE(0, 0);
  __syncthreads();
  int cur = 0;
  for (int k0 = 0; k0 < K; k0 += BK) {
    if (k0 + BK < K) STAGE(cur ^ 1, k0 + BK);  // overlap with compute
#pragma unroll
    for (int kk = 0; kk < BK / 32; ++kk) {
      bf16x8 af[MR], bfr[NR];
#pragma unroll
      for (int i = 0; i < MR; ++i) {
        const int row = wm + i * 16 + lr;
        af[i] = *(const bf16x8*)&As[cur][row * BK +
                                         (((kk * 4 + lg) ^ (row & 7)) * 8)];
      }
#pragma unroll
      for (int j = 0; j < NR; ++j) {
        const int row = wn + j * 16 + lr;
        bfr[j] = *(const bf16x8*)&Bs[cur][row * BK +
                                          (((kk * 4 + lg) ^ (row & 7)) * 8)];
      }
      __builtin_amdgcn_s_setprio(1);
#pragma unroll
      for (int i = 0; i < MR; ++i)
#pragma unroll
        for (int j = 0; j < NR; ++j)
          acc[i][j] = __builtin_amdgcn_mfma_f32_16x16x32_bf16(
              af[i], bfr[j], acc[i][j], 0, 0, 0);
      __builtin_amdgcn_s_setprio(0);
    }
    __syncthreads();  // drains vmcnt(0): next tile staged + cur reusable
    cur ^= 1;
  }

  // epilogue: C/D layout col = l&15, row = (l>>4)*4 + t  [m89-verified]
#pragma unroll
  for (int i = 0; i < MR; ++i) {
#pragma unroll
    for (int j = 0; j < NR; ++j) {
#pragma unroll
      for (int t = 0; t < 4; ++t) {
        const int grow = m0 + wm + i * 16 + lg * 4 + t;
        const int gcol = n0 + wn + j * 16 + lr;
        const float v = acc[i][j][t];
        if (EPI == 0) {
          ((u16*)Cout)[(size_t)grow * N + gcol] = f2bf(v);
        } else if (EPI == 1) {
          const size_t idx = (size_t)grow * N + gcol;
          ((float*)Cout)[idx] = ((const float*)auxp)[idx] + v;
        } else if (EPI == 2) {
          const size_t idx = (size_t)grow * N + gcol;
          const float av = bf2f(((const u16*)auxp)[idx]);
          const float sw = av / (1.f + __expf(-av));
          ((u16*)Cout)[idx] = f2bf(sw * v);
        } else {
          u16* base = (u16*)Cout + (size_t)(gcol >> 10) * ((size_t)M_ * D_);
          base[(size_t)grow * D_ + (gcol & 1023)] = f2bf(v);
        }
      }
    }
  }
}

// ---------------------------------------------------------------------------
// Causal flash attention. Q pre-scaled by 1/8 in RoPE. KVBLK=64, dbuf LDS,
// XOR-swizzled K/V tiles, full/diagonal tile split, defer-max (THR=8).
__global__ __launch_bounds__(256) void attn_fwd(const u16* __restrict__ Q,
                                                const u16* __restrict__ K,
                                                const u16* __restrict__ Vt,
                                                u16* __restrict__ O) {
  __shared__ __align__(16) u16 Ks[2][64 * 64];
  __shared__ __align__(16) u16 Vs[2][64 * 64];
  __shared__ __align__(16) u16 Ps[4][16 * 72];
  const int tid = threadIdx.x, l = tid & 63, w = tid >> 6;
  const int lr = l & 15, lg = l >> 4;
  const int bid = blockIdx.x;
  const int xcd = bid & 7, i = bid >> 3;
  const int bh = xcd * 4 + (i >> 5);  // 4 heads per XCD
  const int qx = 31 - (i & 31);       // heavy first
  const int b = bh >> 4, h = bh & 15;
  const int q0w = qx * 64 + w * 16;

  const u16* Kb = K + (size_t)(b * S_) * D_ + h * DK_;
  const u16* Vb = Vt + (size_t)bh * DK_ * S_;

  bf16x8 aq[2];
  {
    const u16* qp = Q + (size_t)(b * S_ + q0w + lr) * D_ + h * DK_ + lg * 8;
    aq[0] = *(const bf16x8*)qp;
    aq[1] = *(const bf16x8*)(qp + 32);
  }
  f32x4 oacc[4] = {};
  float mrow[4], lrow[4];
#pragma unroll
  for (int t = 0; t < 4; ++t) { mrow[t] = -1e30f; lrow[t] = 0.f; }

  auto STAGE = [&](int bf, int t) {
#pragma unroll
    for (int inst = 0; inst < 2; ++inst) {
      const int s = (w * 2 + inst) * 64 + l;
      const int r = s >> 3, ch = s & 7;
      const int chs = ch ^ (r & 7);
      async_lds16(Kb + (size_t)(t * 64 + r) * D_ + chs * 8,
                  (char*)Ks[bf] + (w * 2 + inst) * 1024);
      async_lds16(Vb + (size_t)r * S_ + t * 64 + chs * 8,
                  (char*)Vs[bf] + (w * 2 + inst) * 1024);
    }
  };

  auto QKT = [&](int cur, f32x4* sf) {
    __builtin_amdgcn_s_setprio(1);
#pragma unroll
    for (int n = 0; n < 4; ++n) {
      const int kvr = n * 16 + lr;
      f32x4 z = {};
#pragma unroll
      for (int ss = 0; ss < 2; ++ss) {
        const int cw = ss * 4 + lg;
        bf16x8 bk = *(const bf16x8*)&Ks[cur][kvr * 64 + ((cw ^ (kvr & 7)) * 8)];
        z = __builtin_amdgcn_mfma_f32_16x16x32_bf16(aq[ss], bk, z, 0, 0, 0);
      }
      sf[n] = z;
    }
    __builtin_amdgcn_s_setprio(0);
  };

  auto PV = [&](int cur) {
    bf16x8 ap0 = *(const bf16x8*)&Ps[w][lr * 72 + lg * 8];
    bf16x8 ap1 = *(const bf16x8*)&Ps[w][lr * 72 + 32 + lg * 8];
    __builtin_amdgcn_s_setprio(1);
#pragma unroll
    for (int d = 0; d < 4; ++d) {
      const int row = d * 16 + lr;
      bf16x8 bv0 = *(const bf16x8*)&Vs[cur][row * 64 + ((lg ^ (row & 7)) * 8)];
      bf16x8 bv1 =
          *(const bf16x8*)&Vs[cur][row * 64 + (((4 + lg) ^ (row & 7)) * 8)];
      oacc[d] = __builtin_amdgcn_mfma_f32_16x16x32_bf16(ap0, bv0, oacc[d], 0, 0, 0);
      oacc[d] = __builtin_amdgcn_mfma_f32_16x16x32_bf16(ap1, bv1, oacc[d], 0, 0, 0);
    }
    __builtin_amdgcn_s_setprio(0);
  };

  STAGE(0, 0);
  __syncthreads();
  int cur = 0;
  // FULL tiles (kv strictly below all q rows of this wave): no causal mask.
  for (int it = 0; it < qx; ++it) {
    STAGE(cur ^ 1, it + 1);
    f32x4 sf[4];
    QKT(cur, sf);
    // defer-max: in-lane check only; reduce+rescale only when needed
    float fm[4];
    bool exc = false;
#pragma unroll
    for (int t = 0; t < 4; ++t) {
      fm[t] = fmaxf(fmaxf(sf[0][t], sf[1][t]), fmaxf(sf[2][t], sf[3][t]));
      exc |= fm[t] > mrow[t] + 8.f;
    }
    if (__any(exc)) {
#pragma unroll
      for (int t = 0; t < 4; ++t) {
        float mx = fm[t];
#pragma unroll
        for (int off = 1; off < 16; off <<= 1)
          mx = fmaxf(mx, __shfl_xor(mx, off));
        const float nm = fmaxf(mrow[t], mx);
        const float c = __expf(mrow[t] - nm);
        mrow[t] = nm;
        lrow[t] *= c;
#pragma unroll
        for (int d = 0; d < 4; ++d) oacc[d][t] *= c;
      }
    }
#pragma unroll
    for (int t = 0; t < 4; ++t) {
      float ps = 0.f;
#pragma unroll
      for (int n = 0; n < 4; ++n) {
        const float e = __expf(sf[n][t] - mrow[t]);
        ps += e;
        Ps[w][(lg * 4 + t) * 72 + n * 16 + lr] = f2bf(e);
      }
#pragma unroll
      for (int off = 1; off < 16; off <<= 1) ps += __shfl_xor(ps, off);
      lrow[t] += ps;
    }
    PV(cur);
    __syncthreads();
    cur ^= 1;
  }
  // DIAGONAL tile (it = qx): causal mask + always-rescale path.
  {
    const int kv0 = qx * 64;
    f32x4 sf[4];
    QKT(cur, sf);
#pragma unroll
    for (int t = 0; t < 4; ++t) {
      const int qrow = q0w + lg * 4 + t;
      float v[4];
#pragma unroll
      for (int n = 0; n < 4; ++n)
        v[n] = (kv0 + n * 16 + lr <= qrow) ? sf[n][t] : -1e30f;
      float mx = fmaxf(fmaxf(v[0], v[1]), fmaxf(v[2], v[3]));
#pragma unroll
      for (int off = 1; off < 16; off <<= 1) mx = fmaxf(mx, __shfl_xor(mx, off));
      const float nm = fmaxf(mrow[t], mx);
      float e[4], ps = 0.f;
#pragma unroll
      for (int n = 0; n < 4; ++n) { e[n] = __expf(v[n] - nm); ps += e[n]; }
#pragma unroll
      for (int off = 1; off < 16; off <<= 1) ps += __shfl_xor(ps, off);
      const float c = __expf(mrow[t] - nm);
      lrow[t] = lrow[t] * c + ps;
      mrow[t] = nm;
#pragma unroll
      for (int d = 0; d < 4; ++d) oacc[d][t] *= c;
#pragma unroll
      for (int n = 0; n < 4; ++n)
        Ps[w][(lg * 4 + t) * 72 + n * 16 + lr] = f2bf(e[n]);
    }
    PV(cur);
  }
#pragma unroll
  for (int d = 0; d < 4; ++d) {
#pragma unroll
    for (int t = 0; t < 4; ++t) {
      const size_t idx =
          (size_t)(b * S_ + q0w + lg * 4 + t) * D_ + h * DK_ + d * 16 + lr;
      O[idx] = f2bf(oacc[d][t] / lrow[t]);
    }
  }
}

// ---------------------------------------------------------------------------
extern "C" void kernel_launch(void* const* d_in, const int* in_sizes, int n_in,
                              void* d_out, int out_size, void* d_ws,
                              size_t ws_size, hipStream_t stream) {
  (void)in_sizes; (void)n_in; (void)out_size; (void)ws_size;
  const float* x = (const float*)d_in[0];
  const float* wq = (const float*)d_in[1];
  const float* wk = (const float*)d_in[2];
  const float* wv = (const float*)d_in[3];
  const float* wo = (const float*)d_in[4];
  const float* w1 = (const float*)d_in[5];
  const float* w2 = (const float*)d_in[6];
  const float* w3 = (const float*)d_in[7];
  const float* g1 = (const float*)d_in[8];
  const float* g2 = (const float*)d_in[9];
  const int* tp = (const int*)d_in[10];
  float* out = (float*)d_out;

  char* ws = (char*)d_ws;
  const size_t MB = 1024u * 1024u;
  u16* wqkvb = (u16*)(ws + 0 * MB);   // [3072][1024] = 6MB
  u16* wob = (u16*)(ws + 6 * MB);
  u16* w1b = (u16*)(ws + 8 * MB);
  u16* w2b = (u16*)(ws + 16 * MB);
  u16* w3b = (u16*)(ws + 24 * MB);
  u16* hb  = (u16*)(ws + 32 * MB);    // rmsnorm1 out; later attn-out
  float* yb = (float*)(ws + 40 * MB); // 16MB f32
  u16* h2b = (u16*)(ws + 56 * MB);
  u16* Qb  = (u16*)(ws + 64 * MB);    // Q/K/V contiguous (EPI3 split store)
  u16* Kb  = (u16*)(ws + 72 * MB);
  u16* Vb  = (u16*)(ws + 80 * MB);
  u16* Vtb = (u16*)(ws + 88 * MB);
  u16* ab  = (u16*)(ws + 64 * MB);    // 32MB, reuses Q/K/V/Vt after attention
  u16* ffb = (u16*)(ws + 96 * MB);    // 32MB
  u16* aob = hb;

  f2b_all<<<16384, 256, 0, stream>>>(wq, wk, wv, wo, w1, w2, w3, wqkvb, wob,
                                     w1b, w2b, w3b);

  rmsnorm_k<<<4096, 256, 0, stream>>>(x, g1, hb);

  // fused QKV projection: N=3072, 256^2 tiles BK=64, split into Qb/Kb/Vb
  gemm2ph<256, 256, 64, 3><<<dim3(12, 16), 512, 0, stream>>>(
      hb, wqkvb, Qb, nullptr, 3072, 1024);

  rope2_k<<<16384, 256, 0, stream>>>((unsigned int*)Qb, (unsigned int*)Kb, tp);
  transpose_v<<<dim3(64, 32), 256, 0, stream>>>(Vb, Vtb);

  attn_fwd<<<1024, 256, 0, stream>>>(Qb, Kb, Vtb, aob);

  // WO: 128^2 tiles, BK=128 (8 K-steps, 32 MFMA/wave/step)
  gemm2ph<128, 128, 128, 1><<<dim3(8, 32), 512, 0, stream>>>(aob, wob, yb, x,
                                                             1024, 1024);
  rmsnorm_k<<<4096, 256, 0, stream>>>(yb, g2, h2b);

  gemm2ph<256, 256, 64, 0><<<dim3(16, 16), 512, 0, stream>>>(
      h2b, w1b, ab, nullptr, 4096, 1024);
  gemm2ph<256, 256, 64, 2><<<dim3(16, 16), 512, 0, stream>>>(h2b, w3b, ffb, ab,
                                                             4096, 1024);
  // W2: 128^2 tiles, BK=128 (32 K-steps)
  gemm2ph<128, 128, 128, 1><<<dim3(8, 32), 512, 0, stream>>>(ffb, w2b, out, yb,
                                                             1024, 4096);
}